// Round 1
// baseline (1036.612 us; speedup 1.0000x reference)
//
#include <hip/hip_runtime.h>
#include <math.h>

#define BB 4
#define SS 2048
#define DD 1024
#define NHD 8
#define DHD 128

// ---------------------------------------------------------------------------
// Kernel 1: gates.  ig/fg[(b,h,t)] = qkv[b,t,:] @ W[:,h] + bias.
// 4 rows (t values) per 64-lane wave; each lane strides the 3072-dim K axis.
// ---------------------------------------------------------------------------
__global__ __launch_bounds__(64) void gates_kernel(
    const float* __restrict__ q, const float* __restrict__ k, const float* __restrict__ v,
    const float* __restrict__ Wi, const float* __restrict__ bi,
    const float* __restrict__ Wf, const float* __restrict__ bf,
    float* __restrict__ ig_ws, float* __restrict__ lf_ws) {
  const int lane = threadIdx.x;
  const int g0 = blockIdx.x * 4;          // first global row (b*S + t)
  const int b  = g0 >> 11;                // / SS
  const int t0 = g0 & (SS - 1);

  float acc[64];                           // [4 rows][16 gates] 0..7 = i, 8..15 = f
  #pragma unroll
  for (int i = 0; i < 64; ++i) acc[i] = 0.f;

  const float* rowq = q + (size_t)b * SS * DD + (size_t)t0 * DD;
  const float* rowk = k + (size_t)b * SS * DD + (size_t)t0 * DD;
  const float* rowv = v + (size_t)b * SS * DD + (size_t)t0 * DD;

  #pragma unroll 1
  for (int u4 = 0; u4 < 12; ++u4) {
    const int e4  = lane + 64 * u4;       // float4 index 0..767 within 3072
    const int seg = e4 >> 8;              // 0:q 1:k 2:v  (uniform across wave)
    const int off = (e4 & 255) << 2;      // float offset within 1024-row
    const float* base = (seg == 0) ? rowq : (seg == 1) ? rowk : rowv;
    float4 a0 = *(const float4*)(base + off);
    float4 a1 = *(const float4*)(base + DD + off);
    float4 a2 = *(const float4*)(base + 2 * DD + off);
    float4 a3 = *(const float4*)(base + 3 * DD + off);
    const int ew = e4 * 4 * NHD;          // weight float offset of first element
    #pragma unroll
    for (int ee = 0; ee < 4; ++ee) {
      float4 wiA = *(const float4*)(Wi + ew + ee * NHD);
      float4 wiB = *(const float4*)(Wi + ew + ee * NHD + 4);
      float4 wfA = *(const float4*)(Wf + ew + ee * NHD);
      float4 wfB = *(const float4*)(Wf + ew + ee * NHD + 4);
      float w16[16] = {wiA.x, wiA.y, wiA.z, wiA.w, wiB.x, wiB.y, wiB.z, wiB.w,
                       wfA.x, wfA.y, wfA.z, wfA.w, wfB.x, wfB.y, wfB.z, wfB.w};
      float av[4];
      av[0] = (ee == 0) ? a0.x : (ee == 1) ? a0.y : (ee == 2) ? a0.z : a0.w;
      av[1] = (ee == 0) ? a1.x : (ee == 1) ? a1.y : (ee == 2) ? a1.z : a1.w;
      av[2] = (ee == 0) ? a2.x : (ee == 1) ? a2.y : (ee == 2) ? a2.z : a2.w;
      av[3] = (ee == 0) ? a3.x : (ee == 1) ? a3.y : (ee == 2) ? a3.z : a3.w;
      #pragma unroll
      for (int r = 0; r < 4; ++r) {
        #pragma unroll
        for (int cc = 0; cc < 16; ++cc)
          acc[r * 16 + cc] = fmaf(av[r], w16[cc], acc[r * 16 + cc]);
      }
    }
  }

  // block reduce: lds[idx*65 + lane] (pad 65 -> conflict-free both directions)
  __shared__ float lds[64 * 65];
  #pragma unroll
  for (int x = 0; x < 64; ++x) lds[x * 65 + lane] = acc[x];
  __syncthreads();
  float s = 0.f;
  #pragma unroll 4
  for (int l = 0; l < 64; ++l) s += lds[lane * 65 + l];

  const int r  = lane >> 4;
  const int gi = lane & 15;
  const int t  = t0 + r;
  if (gi < 8) {
    float val = s + bi[gi];
    ig_ws[(size_t)(b * NHD + gi) * SS + t] = val;
  } else {
    const int hh = gi - 8;
    float ft = s + bf[hh];
    // stable log_sigmoid
    float lf = fminf(ft, 0.f) - log1pf(expf(-fabsf(ft)));
    lf_ws[(size_t)(b * NHD + hh) * SS + t] = lf;
  }
}

// ---------------------------------------------------------------------------
// Kernel 2: sequential mLSTM scan.
// Grid: (B*NH) * 16 column-splits.  Block = 64 lanes = 1 wave.
// Lane (jj = lane>>3, rgrp = lane&7): column j = cs*8+jj, rows i0 = rgrp*16 (+16).
// c[16] (16 rows x 1 col) and n[16] (replicated per column group) in registers.
// Writes raw (pre-LN) h into d_out's hn region; final c/n/m states at the tail.
// ---------------------------------------------------------------------------
__global__ __launch_bounds__(64) void scan_kernel(
    const float* __restrict__ q, const float* __restrict__ k, const float* __restrict__ v,
    const float* __restrict__ c0, const float* __restrict__ n0, const float* __restrict__ m0,
    const float* __restrict__ ig_ws, const float* __restrict__ lf_ws,
    float* __restrict__ out) {
  const int lane = threadIdx.x;
  const int bid  = blockIdx.x;
  const int bh   = bid >> 4;
  const int cs   = bid & 15;
  const int b    = bh >> 3;
  const int hh   = bh & 7;
  const int jj   = lane >> 3;
  const int j    = cs * 8 + jj;
  const int i0   = (lane & 7) * 16;

  // weaving layout: head h row t = base + h*S*DH + t*DH
  const size_t headoff = (size_t)b * SS * DD + (size_t)hh * SS * DHD;
  const float* qb = q + headoff;
  const float* kb = k + headoff;
  const float* vb = v + headoff;
  const float* igp = ig_ws + (size_t)bh * SS;
  const float* lfp = lf_ws + (size_t)bh * SS;

  float c[16], n[16];
  #pragma unroll
  for (int u = 0; u < 16; ++u) c[u] = c0[((size_t)bh * DHD + i0 + u) * DHD + j];
  #pragma unroll
  for (int u = 0; u < 16; ++u) n[u] = n0[(size_t)bh * DHD + i0 + u];
  float m = m0[bh];

  float* hout = out + (size_t)b * SS * DD + (size_t)hh * DHD + j;  // + t*DD per step
  const float SCALE = 0.08838834764831845f;  // 1/sqrt(128)

  auto loadset = [&](int t, float4* k4, float4* q4, float& vj, float& lf, float& ii) {
    const float* kr = kb + (size_t)t * DHD + i0;
    const float* qr = qb + (size_t)t * DHD + i0;
    #pragma unroll
    for (int u = 0; u < 4; ++u) {
      k4[u] = *(const float4*)(kr + 4 * u);
      q4[u] = *(const float4*)(qr + 4 * u);
    }
    vj = vb[(size_t)t * DHD + j];
    lf = lfp[t];
    ii = igp[t];
  };

  auto compute = [&](int t, const float4* k4, const float4* q4, float vj, float lf, float ii) {
    float mn = fmaxf(lf + m, ii);
    float fa = __expf(lf + m - mn);
    float ia = __expf(ii - mn);
    m = mn;
    float ias = ia * SCALE;
    float hp = 0.f, qnp = 0.f;
    #pragma unroll
    for (int u4 = 0; u4 < 4; ++u4) {
      float kk[4] = {k4[u4].x, k4[u4].y, k4[u4].z, k4[u4].w};
      float qq[4] = {q4[u4].x, q4[u4].y, q4[u4].z, q4[u4].w};
      #pragma unroll
      for (int e = 0; e < 4; ++e) {
        const int u = u4 * 4 + e;
        float a  = ias * kk[e];
        float cn = fmaf(a, vj, fa * c[u]);
        c[u] = cn;
        float nn = fmaf(fa, n[u], a);
        n[u] = nn;
        hp  = fmaf(qq[e], cn, hp);
        qnp = fmaf(qq[e], nn, qnp);
      }
    }
    // reduce across the 8-lane row groups (same jj)
    hp  += __shfl_xor(hp, 1);  hp  += __shfl_xor(hp, 2);  hp  += __shfl_xor(hp, 4);
    qnp += __shfl_xor(qnp, 1); qnp += __shfl_xor(qnp, 2); qnp += __shfl_xor(qnp, 4);
    float den = fmaxf(fabsf(qnp), __expf(-mn)) + 1e-6f;
    float hv  = hp / den;
    if ((lane & 7) == 0) hout[(size_t)t * DD] = hv;
  };

  float4 kA[4], qA[4]; float vA, lfA, iA;
  float4 kB[4], qB[4]; float vB, lfB, iB;
  loadset(0, kA, qA, vA, lfA, iA);
  #pragma unroll 1
  for (int t = 0; t < SS; t += 2) {
    loadset(t + 1, kB, qB, vB, lfB, iB);      // prefetch next step
    compute(t, kA, qA, vA, lfA, iA);
    const int t2 = (t + 2 < SS) ? (t + 2) : (SS - 1);
    loadset(t2, kA, qA, vA, lfA, iA);          // prefetch step after
    compute(t + 1, kB, qB, vB, lfB, iB);
  }

  // final states
  float* cf = out + (size_t)BB * SS * DD + (size_t)bh * DHD * DHD;
  #pragma unroll
  for (int u = 0; u < 16; ++u) cf[(size_t)(i0 + u) * DHD + j] = c[u];
  if (cs == 0 && jj == 0) {
    float* nf = out + (size_t)BB * SS * DD + (size_t)BB * NHD * DHD * DHD + (size_t)bh * DHD;
    #pragma unroll
    for (int u = 0; u < 16; ++u) nf[i0 + u] = n[u];
    if (lane == 0)
      out[(size_t)BB * SS * DD + (size_t)BB * NHD * DHD * DHD + (size_t)BB * NHD * DHD + bh] = m;
  }
}

// ---------------------------------------------------------------------------
// Kernel 3: in-place LayerNorm over each contiguous 128-float row of hn.
// Row R = (b*S + t)*NH + h; one wave per row, 4 rows per 256-thread block.
// ---------------------------------------------------------------------------
__global__ __launch_bounds__(256) void ln_kernel(float* __restrict__ out,
                                                 const float* __restrict__ lnw) {
  const int lane = threadIdx.x & 63;
  const int w    = threadIdx.x >> 6;
  const int R    = blockIdx.x * 4 + w;
  const int hh   = R & 7;
  float* base = out + (size_t)R * DHD;
  float2 x = *(float2*)(base + lane * 2);
  float ssum = x.x + x.y;
  #pragma unroll
  for (int d = 1; d < 64; d <<= 1) ssum += __shfl_xor(ssum, d);
  float mu = ssum * (1.f / 128.f);
  float d0 = x.x - mu, d1 = x.y - mu;
  float vs = d0 * d0 + d1 * d1;
  #pragma unroll
  for (int d = 1; d < 64; d <<= 1) vs += __shfl_xor(vs, d);
  float rs = rsqrtf(vs * (1.f / 128.f) + 1e-6f);
  float2 wv = *(const float2*)(lnw + hh * DHD + lane * 2);
  float2 o;
  o.x = d0 * rs * wv.x;
  o.y = d1 * rs * wv.y;
  *(float2*)(base + lane * 2) = o;
}

extern "C" void kernel_launch(void* const* d_in, const int* in_sizes, int n_in,
                              void* d_out, int out_size, void* d_ws, size_t ws_size,
                              hipStream_t stream) {
  const float* q   = (const float*)d_in[0];
  const float* k   = (const float*)d_in[1];
  const float* v   = (const float*)d_in[2];
  const float* c0  = (const float*)d_in[3];
  const float* n0  = (const float*)d_in[4];
  const float* m0  = (const float*)d_in[5];
  const float* Wi  = (const float*)d_in[6];
  const float* bi  = (const float*)d_in[7];
  const float* Wf  = (const float*)d_in[8];
  const float* bf  = (const float*)d_in[9];
  const float* lnw = (const float*)d_in[10];
  float* out = (float*)d_out;

  float* ig_ws = (float*)d_ws;                       // B*NH*S floats
  float* lf_ws = ig_ws + (size_t)BB * NHD * SS;      // B*NH*S floats (log_sigmoid(fg))

  gates_kernel<<<BB * SS / 4, 64, 0, stream>>>(q, k, v, Wi, bi, Wf, bf, ig_ws, lf_ws);
  scan_kernel<<<BB * NHD * 16, 64, 0, stream>>>(q, k, v, c0, n0, m0, ig_ws, lf_ws, out);
  ln_kernel<<<BB * SS * NHD / 4, 256, 0, stream>>>(out, lnw);
}

// Round 2
// 735.322 us; speedup vs baseline: 1.4097x; 1.4097x over previous
//
#include <hip/hip_runtime.h>
#include <math.h>

#define BB 4
#define SS 2048
#define DD 1024
#define NHD 8
#define DHD 128
#define NC 16
#define CL 128
#define SCALE 0.08838834764831845f

// workspace offsets (in floats)
#define OFF_IG   0
#define OFF_LF   65536
#define OFF_B    131072
#define OFF_G    196608
#define OFF_E    262144
#define OFF_RM   327680
#define OFF_MIN  393216
#define OFF_SC   393728
#define OFF_UN   396288
#define OFF_NIN  461824
#define OFF_U    527360
// out offsets (floats)
#define OUT_C  8388608
#define OUT_N  8912896
#define OUT_M  8916992

// ---------------------------------------------------------------------------
// Kernel 1: gates (unchanged from validated round 1).
// ---------------------------------------------------------------------------
__global__ __launch_bounds__(64) void gates_kernel(
    const float* __restrict__ q, const float* __restrict__ k, const float* __restrict__ v,
    const float* __restrict__ Wi, const float* __restrict__ bi,
    const float* __restrict__ Wf, const float* __restrict__ bf,
    float* __restrict__ ig_ws, float* __restrict__ lf_ws) {
  const int lane = threadIdx.x;
  const int g0 = blockIdx.x * 4;
  const int b  = g0 >> 11;
  const int t0 = g0 & (SS - 1);

  float acc[64];
  #pragma unroll
  for (int i = 0; i < 64; ++i) acc[i] = 0.f;

  const float* rowq = q + (size_t)b * SS * DD + (size_t)t0 * DD;
  const float* rowk = k + (size_t)b * SS * DD + (size_t)t0 * DD;
  const float* rowv = v + (size_t)b * SS * DD + (size_t)t0 * DD;

  #pragma unroll 1
  for (int u4 = 0; u4 < 12; ++u4) {
    const int e4  = lane + 64 * u4;
    const int seg = e4 >> 8;
    const int off = (e4 & 255) << 2;
    const float* base = (seg == 0) ? rowq : (seg == 1) ? rowk : rowv;
    float4 a0 = *(const float4*)(base + off);
    float4 a1 = *(const float4*)(base + DD + off);
    float4 a2 = *(const float4*)(base + 2 * DD + off);
    float4 a3 = *(const float4*)(base + 3 * DD + off);
    const int ew = e4 * 4 * NHD;
    #pragma unroll
    for (int ee = 0; ee < 4; ++ee) {
      float4 wiA = *(const float4*)(Wi + ew + ee * NHD);
      float4 wiB = *(const float4*)(Wi + ew + ee * NHD + 4);
      float4 wfA = *(const float4*)(Wf + ew + ee * NHD);
      float4 wfB = *(const float4*)(Wf + ew + ee * NHD + 4);
      float w16[16] = {wiA.x, wiA.y, wiA.z, wiA.w, wiB.x, wiB.y, wiB.z, wiB.w,
                       wfA.x, wfA.y, wfA.z, wfA.w, wfB.x, wfB.y, wfB.z, wfB.w};
      float av[4];
      av[0] = (ee == 0) ? a0.x : (ee == 1) ? a0.y : (ee == 2) ? a0.z : a0.w;
      av[1] = (ee == 0) ? a1.x : (ee == 1) ? a1.y : (ee == 2) ? a1.z : a1.w;
      av[2] = (ee == 0) ? a2.x : (ee == 1) ? a2.y : (ee == 2) ? a2.z : a2.w;
      av[3] = (ee == 0) ? a3.x : (ee == 1) ? a3.y : (ee == 2) ? a3.z : a3.w;
      #pragma unroll
      for (int r = 0; r < 4; ++r) {
        #pragma unroll
        for (int cc = 0; cc < 16; ++cc)
          acc[r * 16 + cc] = fmaf(av[r], w16[cc], acc[r * 16 + cc]);
      }
    }
  }

  __shared__ float lds[64 * 65];
  #pragma unroll
  for (int x = 0; x < 64; ++x) lds[x * 65 + lane] = acc[x];
  __syncthreads();
  float s = 0.f;
  #pragma unroll 4
  for (int l = 0; l < 64; ++l) s += lds[lane * 65 + l];

  const int r  = lane >> 4;
  const int gi = lane & 15;
  const int t  = t0 + r;
  if (gi < 8) {
    ig_ws[(size_t)(b * NHD + gi) * SS + t] = s + bi[gi];
  } else {
    const int hh = gi - 8;
    float ft = s + bf[hh];
    float lf = fminf(ft, 0.f) - log1pf(expf(-fabsf(ft)));
    lf_ws[(size_t)(b * NHD + hh) * SS + t] = lf;
  }
}

// ---------------------------------------------------------------------------
// Kernel 2: prep — per (b,h): within-chunk cumsum B, G=i-B, M_s, E=exp(G-mxG),
// per-chunk m_in, and the stabilized prefix-combination scalars.
// ---------------------------------------------------------------------------
__global__ __launch_bounds__(128) void prep_kernel(float* __restrict__ ws,
                                                   const float* __restrict__ m0,
                                                   float* __restrict__ out) {
  const int bh = blockIdx.x;
  const int s  = threadIdx.x;
  __shared__ float sh[128];
  __shared__ float bc2[2];
  __shared__ float mina[NC], mxga[NC], lfsa[NC];
  const float* lf = ws + OFF_LF + (size_t)bh * SS;
  const float* ig = ws + OFF_IG + (size_t)bh * SS;
  const float m0v = m0[bh];
  float m_run = m0v, LFtot = 0.f;
  for (int g = 0; g < NC; ++g) {
    const int t = g * CL + s;
    float lfv = lf[t], iv = ig[t];
    // inclusive cumsum of lf
    float v = lfv;
    sh[s] = v; __syncthreads();
    for (int off = 1; off < 128; off <<= 1) {
      float tv = (s >= off) ? sh[s - off] : 0.f;
      __syncthreads();
      v += tv; sh[s] = v; __syncthreads();
    }
    float Bv = v;
    float Gv = iv - Bv;
    // inclusive running max of G
    v = Gv; sh[s] = v; __syncthreads();
    for (int off = 1; off < 128; off <<= 1) {
      float tv = (s >= off) ? sh[s - off] : -3.0e38f;
      __syncthreads();
      v = fmaxf(v, tv); sh[s] = v; __syncthreads();
    }
    float Rv = v;
    if (s == 127) { bc2[0] = Bv; bc2[1] = Rv; }
    __syncthreads();
    float Bend = bc2[0], mxG = bc2[1];
    __syncthreads();
    ws[OFF_B  + (size_t)bh * SS + t] = Bv;
    ws[OFF_G  + (size_t)bh * SS + t] = Gv;
    ws[OFF_RM + (size_t)bh * SS + t] = fmaxf(m_run, Rv);   // = M_s directly
    ws[OFF_E  + (size_t)bh * SS + t] = expf(Gv - mxG);
    if (s == 0) {
      ws[OFF_MIN + bh * NC + g] = m_run;
      mina[g] = m_run; mxga[g] = mxG; lfsa[g] = LFtot;
    }
    m_run = Bend + fmaxf(m_run, mxG);
    LFtot += Bend;
  }
  if (s == 0) {
    out[OUT_M + bh] = m_run;
    float* sc = ws + OFF_SC + bh * 80;
    float S = -3.0e38f;
    for (int g = 0; g < NC; ++g) {
      float r_g = lfsa[g] - mina[g];
      sc[g]      = expf(S + r_g);                 // wC
      sc[20 + g] = expf(m0v + lfsa[g] - mina[g]); // z
      float s_g = mxga[g] - lfsa[g];
      float Sn = fmaxf(S, s_g);
      sc[40 + g] = expf(S - Sn);                  // wP
      sc[60 + g] = expf(s_g - Sn);                // wU
      S = Sn;
    }
    float r16 = LFtot - m_run;
    sc[16] = expf(S + r16);
    sc[36] = expf(m0v + LFtot - m_run);
  }
}

// ---------------------------------------------------------------------------
// Kernel 3: per-chunk unweighted state sums U^(g) = sum_r E_r * k̂_r v_r^T.
// Grid: bh(32) x g(16) x jtile(16); 64 lanes; lane = 8 cols x 8 rowgroups.
// ---------------------------------------------------------------------------
__global__ __launch_bounds__(64) void u_kernel(const float* __restrict__ k,
                                               const float* __restrict__ v,
                                               float* __restrict__ ws) {
  const int lane = threadIdx.x;
  const int jt = blockIdx.x & 15;
  const int g  = (blockIdx.x >> 4) & 15;
  const int bh = blockIdx.x >> 8;
  const int b = bh >> 3, hh = bh & 7;
  const int j  = jt * 8 + (lane >> 3);
  const int i0 = (lane & 7) * 16;
  const size_t headoff = (size_t)b * SS * DD + (size_t)hh * SS * DHD;
  const float* kb = k + headoff + (size_t)g * CL * DHD;
  const float* vb = v + headoff + (size_t)g * CL * DHD;
  const float* E  = ws + OFF_E + (size_t)bh * SS + g * CL;
  float acc[16];
  #pragma unroll
  for (int u = 0; u < 16; ++u) acc[u] = 0.f;
  #pragma unroll 2
  for (int r = 0; r < CL; ++r) {
    float ev = E[r] * SCALE * vb[(size_t)r * DHD + j];
    const float* kr = kb + (size_t)r * DHD + i0;
    float4 k0 = *(const float4*)(kr);
    float4 k1 = *(const float4*)(kr + 4);
    float4 k2 = *(const float4*)(kr + 8);
    float4 k3 = *(const float4*)(kr + 12);
    acc[0]  += ev * k0.x; acc[1]  += ev * k0.y; acc[2]  += ev * k0.z; acc[3]  += ev * k0.w;
    acc[4]  += ev * k1.x; acc[5]  += ev * k1.y; acc[6]  += ev * k1.z; acc[7]  += ev * k1.w;
    acc[8]  += ev * k2.x; acc[9]  += ev * k2.y; acc[10] += ev * k2.z; acc[11] += ev * k2.w;
    acc[12] += ev * k3.x; acc[13] += ev * k3.y; acc[14] += ev * k3.z; acc[15] += ev * k3.w;
  }
  float* Ubuf = ws + OFF_U + (size_t)(bh * NC + g) * (DHD * DHD);
  #pragma unroll
  for (int u = 0; u < 16; ++u) Ubuf[(size_t)(i0 + u) * DHD + j] = acc[u];
}

// Kernel 3b: Un^(g)[i] = sum_r E_r * k̂_r[i]
__global__ __launch_bounds__(128) void un_kernel(const float* __restrict__ k,
                                                 float* __restrict__ ws) {
  const int i = threadIdx.x;
  const int g = blockIdx.x & 15;
  const int bh = blockIdx.x >> 4;
  const int b = bh >> 3, hh = bh & 7;
  const float* kb = k + (size_t)b * SS * DD + (size_t)hh * SS * DHD + (size_t)g * CL * DHD;
  const float* E = ws + OFF_E + (size_t)bh * SS + g * CL;
  float acc = 0.f;
  #pragma unroll 4
  for (int r = 0; r < CL; ++r) acc += E[r] * SCALE * kb[(size_t)r * DHD + i];
  ws[OFF_UN + (size_t)(bh * NC + g) * DHD + i] = acc;
}

// ---------------------------------------------------------------------------
// Kernel 4: stabilized weighted prefix over chunks; writes C_in^(g) in place
// over U^(g); final state to out tail.  One element per thread.
// ---------------------------------------------------------------------------
__global__ __launch_bounds__(256) void cprefix_kernel(const float* __restrict__ c0,
                                                      float* __restrict__ ws,
                                                      float* __restrict__ out) {
  const int bh = blockIdx.x >> 6;
  const int elem = ((blockIdx.x & 63) << 8) + threadIdx.x;
  const float* sc = ws + OFF_SC + bh * 80;
  float c0v = c0[(size_t)bh * 16384 + elem];
  float* Ub = ws + OFF_U + (size_t)bh * NC * 16384 + elem;
  float P = 0.f;
  #pragma unroll 1
  for (int g = 0; g < NC; ++g) {
    float u = Ub[(size_t)g * 16384];
    Ub[(size_t)g * 16384] = sc[g] * P + sc[20 + g] * c0v;
    P = sc[40 + g] * P + sc[60 + g] * u;
  }
  out[OUT_C + (size_t)bh * 16384 + elem] = sc[16] * P + sc[36] * c0v;
}

__global__ __launch_bounds__(128) void nprefix_kernel(const float* __restrict__ n0,
                                                      float* __restrict__ ws,
                                                      float* __restrict__ out) {
  const int bh = blockIdx.x;
  const int i = threadIdx.x;
  const float* sc = ws + OFF_SC + bh * 80;
  float n0v = n0[bh * DHD + i];
  const float* Ub = ws + OFF_UN + (size_t)bh * NC * DHD + i;
  float* Nb = ws + OFF_NIN + (size_t)bh * NC * DHD + i;
  float P = 0.f;
  #pragma unroll 1
  for (int g = 0; g < NC; ++g) {
    float u = Ub[g * DHD];
    Nb[g * DHD] = sc[g] * P + sc[20 + g] * n0v;
    P = sc[40 + g] * P + sc[60 + g] * u;
  }
  out[OUT_N + bh * DHD + i] = sc[16] * P + sc[36] * n0v;
}

// ---------------------------------------------------------------------------
// Kernel 5: intra-chunk attention + inter term + denom + fused LayerNorm.
// Grid: bh(32) x g(16) x shalf(2); 256 threads = 4 waves.
// Wave qr handles r-range (phase A) / j-range (phase B) = qr*32; lane = s row.
// ---------------------------------------------------------------------------
__global__ __launch_bounds__(256) void intra_kernel(
    const float* __restrict__ q, const float* __restrict__ k, const float* __restrict__ v,
    const float* __restrict__ lnw, float* __restrict__ ws, float* __restrict__ out) {
  const int tid = threadIdx.x;
  const int sl = tid & 63;
  const int qr = tid >> 6;
  const int shalf = blockIdx.x & 1;
  const int g = (blockIdx.x >> 1) & 15;
  const int bh = blockIdx.x >> 5;
  const int b = bh >> 3, hh = bh & 7;
  const int sg = shalf * 64 + sl;
  const int t0 = g * CL;

  __shared__ float Ssh[64 * 129];
  __shared__ float Gs[128], Ms2[128], ninS[128];
  __shared__ float Bsl2[64];
  __shared__ float qnp[64 * 4], mup[64 * 4], sqp[64 * 4];

  const size_t headoff = (size_t)b * SS * DD + (size_t)hh * SS * DHD;
  const float* qb = q + headoff;
  const float* kb = k + headoff;
  const float* vb = v + headoff;

  if (tid < 128) {
    Gs[tid]   = ws[OFF_G  + (size_t)bh * SS + t0 + tid];
    Ms2[tid]  = ws[OFF_RM + (size_t)bh * SS + t0 + tid];
    ninS[tid] = ws[OFF_NIN + (size_t)(bh * NC + g) * DHD + tid];
  }
  if (tid < 64) Bsl2[tid] = ws[OFF_B + (size_t)bh * SS + t0 + shalf * 64 + tid];
  qnp[tid] = 0.f;
  __syncthreads();

  const float m_in  = ws[OFF_MIN + bh * NC + g];
  const float Msv   = Ms2[sg];
  const float alpha = __expf(m_in - Msv);

  // ---- phase A: SW[s][r] = mask*exp(G_r - M_s)*scale*(q_s . k_r) ----
  const int rbase = qr * 32;
  const bool awork = rbase < (shalf ? 128 : 64);
  float acc[32];
  #pragma unroll
  for (int u = 0; u < 32; ++u) acc[u] = 0.f;
  float qn2 = 0.f;
  const float* qrow = qb + (size_t)(t0 + sg) * DHD;
  #pragma unroll 1
  for (int kk = 0; kk < 4; ++kk) {
    float4 qv[8];
    #pragma unroll
    for (int u = 0; u < 8; ++u) qv[u] = *(const float4*)(qrow + kk * 32 + u * 4);
    #pragma unroll
    for (int u = 0; u < 8; ++u) {
      const int d = kk * 32 + u * 4;
      qn2 += qv[u].x * ninS[d] + qv[u].y * ninS[d + 1] +
             qv[u].z * ninS[d + 2] + qv[u].w * ninS[d + 3];
    }
    if (awork) {
      #pragma unroll 4
      for (int rr = 0; rr < 32; ++rr) {
        const float* krow = kb + (size_t)(t0 + rbase + rr) * DHD + kk * 32;
        float a = acc[rr];
        #pragma unroll
        for (int u = 0; u < 8; ++u) {
          float4 kv = *(const float4*)(krow + u * 4);
          a += qv[u].x * kv.x + qv[u].y * kv.y + qv[u].z * kv.z + qv[u].w * kv.w;
        }
        acc[rr] = a;
      }
    }
  }
  float qnr = 0.f;
  if (awork) {
    #pragma unroll 4
    for (int rr = 0; rr < 32; ++rr) {
      const int r = rbase + rr;
      float w = (r <= sg) ? __expf(Gs[r] - Msv) * SCALE : 0.f;
      float swv = acc[rr] * w;
      Ssh[sl * 129 + r] = swv;
      qnr += swv;
    }
  }
  qnp[sl * 4 + qr] = qnr;
  __syncthreads();

  // ---- phase B: H = SW@V + alpha * Q@C_in ----
  const int jb = qr * 32;
  float acc2[32];
  #pragma unroll
  for (int u = 0; u < 32; ++u) acc2[u] = 0.f;
  const int RMAX = shalf ? 128 : 64;
  #pragma unroll 2
  for (int r = 0; r < RMAX; ++r) {
    float swv = Ssh[sl * 129 + r];
    const float* vrow = vb + (size_t)(t0 + r) * DHD + jb;
    #pragma unroll
    for (int u = 0; u < 8; ++u) {
      float4 vv = *(const float4*)(vrow + u * 4);
      acc2[u * 4 + 0] += swv * vv.x; acc2[u * 4 + 1] += swv * vv.y;
      acc2[u * 4 + 2] += swv * vv.z; acc2[u * 4 + 3] += swv * vv.w;
    }
  }
  const float* cinb = ws + OFF_U + (size_t)(bh * NC + g) * (DHD * DHD);
  #pragma unroll 1
  for (int dd = 0; dd < 16; ++dd) {
    float4 q0 = *(const float4*)(qrow + dd * 8);
    float4 q1 = *(const float4*)(qrow + dd * 8 + 4);
    float qe[8] = {q0.x, q0.y, q0.z, q0.w, q1.x, q1.y, q1.z, q1.w};
    #pragma unroll
    for (int e = 0; e < 8; ++e) {
      float coef = alpha * qe[e];
      const float* crow = cinb + (size_t)(dd * 8 + e) * DHD + jb;
      #pragma unroll
      for (int u = 0; u < 8; ++u) {
        float4 cv = *(const float4*)(crow + u * 4);
        acc2[u * 4 + 0] += coef * cv.x; acc2[u * 4 + 1] += coef * cv.y;
        acc2[u * 4 + 2] += coef * cv.z; acc2[u * 4 + 3] += coef * cv.w;
      }
    }
  }
  // denom + h
  float qnv = qnp[sl * 4 + 0] + qnp[sl * 4 + 1] + qnp[sl * 4 + 2] + qnp[sl * 4 + 3]
            + alpha * qn2;
  float den = fmaxf(fabsf(qnv), __expf(-(Bsl2[sl] + Msv))) + 1e-6f;
  float inv = 1.0f / den;
  float mp = 0.f, sp = 0.f;
  #pragma unroll
  for (int u = 0; u < 32; ++u) {
    acc2[u] *= inv;
    mp += acc2[u];
    sp += acc2[u] * acc2[u];
  }
  mup[sl * 4 + qr] = mp; sqp[sl * 4 + qr] = sp;
  __syncthreads();
  float mu  = (mup[sl * 4] + mup[sl * 4 + 1] + mup[sl * 4 + 2] + mup[sl * 4 + 3]) * (1.f / 128.f);
  float ssq = (sqp[sl * 4] + sqp[sl * 4 + 1] + sqp[sl * 4 + 2] + sqp[sl * 4 + 3]) * (1.f / 128.f);
  float var = fmaxf(ssq - mu * mu, 0.f);
  float rstd = rsqrtf(var + 1e-6f);
  float* orow = out + (size_t)(b * SS + t0 + sg) * DD + hh * DHD + jb;
  const float* lw = lnw + hh * DHD + jb;
  #pragma unroll
  for (int u = 0; u < 8; ++u) {
    float4 lv = *(const float4*)(lw + u * 4);
    float4 o;
    o.x = (acc2[u * 4 + 0] - mu) * rstd * lv.x;
    o.y = (acc2[u * 4 + 1] - mu) * rstd * lv.y;
    o.z = (acc2[u * 4 + 2] - mu) * rstd * lv.z;
    o.w = (acc2[u * 4 + 3] - mu) * rstd * lv.w;
    *(float4*)(orow + u * 4) = o;
  }
}

extern "C" void kernel_launch(void* const* d_in, const int* in_sizes, int n_in,
                              void* d_out, int out_size, void* d_ws, size_t ws_size,
                              hipStream_t stream) {
  const float* q   = (const float*)d_in[0];
  const float* k   = (const float*)d_in[1];
  const float* v   = (const float*)d_in[2];
  const float* c0  = (const float*)d_in[3];
  const float* n0  = (const float*)d_in[4];
  const float* m0  = (const float*)d_in[5];
  const float* Wi  = (const float*)d_in[6];
  const float* bi  = (const float*)d_in[7];
  const float* Wf  = (const float*)d_in[8];
  const float* bf  = (const float*)d_in[9];
  const float* lnw = (const float*)d_in[10];
  float* out = (float*)d_out;
  float* ws  = (float*)d_ws;

  gates_kernel<<<BB * SS / 4, 64, 0, stream>>>(q, k, v, Wi, bi, Wf, bf,
                                               ws + OFF_IG, ws + OFF_LF);
  prep_kernel<<<BB * NHD, 128, 0, stream>>>(ws, m0, out);
  u_kernel<<<BB * NHD * NC * 16, 64, 0, stream>>>(k, v, ws);
  un_kernel<<<BB * NHD * NC, 128, 0, stream>>>(k, ws);
  cprefix_kernel<<<BB * NHD * 64, 256, 0, stream>>>(c0, ws, out);
  nprefix_kernel<<<BB * NHD, 128, 0, stream>>>(n0, ws, out);
  intra_kernel<<<BB * NHD * NC * 2, 256, 0, stream>>>(q, k, v, lnw, ws, out);
}

// Round 4
// 390.704 us; speedup vs baseline: 2.6532x; 1.8820x over previous
//
#include <hip/hip_runtime.h>
#include <math.h>

#define BB 4
#define SS 2048
#define DD 1024
#define NHD 8
#define DHD 128
#define NC 16
#define CL 128
#define SCALE 0.08838834764831845f

// workspace offsets (in floats)
#define OFF_IG   0
#define OFF_LF   65536
#define OFF_B    131072
#define OFF_G    196608
#define OFF_E    262144
#define OFF_RM   327680
#define OFF_MIN  393216
#define OFF_SC   393728
#define OFF_UN   396288
#define OFF_NIN  461824
#define OFF_U    527360
// out offsets (floats)
#define OUT_C  8388608
#define OUT_N  8912896
#define OUT_M  8916992

typedef __attribute__((ext_vector_type(8))) _Float16 f16x8;
typedef __attribute__((ext_vector_type(4))) float f32x4;

__device__ __forceinline__ unsigned pk2h(float a, float b) {
  union { _Float16 h[2]; unsigned u; } f;
  f.h[0] = (_Float16)a; f.h[1] = (_Float16)b;
  return f.u;
}
__device__ __forceinline__ f16x8 mkfrag(float4 a, float4 c) {
  f16x8 f;
  f[0] = (_Float16)a.x; f[1] = (_Float16)a.y; f[2] = (_Float16)a.z; f[3] = (_Float16)a.w;
  f[4] = (_Float16)c.x; f[5] = (_Float16)c.y; f[6] = (_Float16)c.z; f[7] = (_Float16)c.w;
  return f;
}
// 256B rows, XOR-swizzle byte bits 4..6 with row&7 (m214 attn recipe)
__device__ __forceinline__ char* swp(char* base, int row, int byte) {
  return base + (((row << 8) + byte) ^ ((row & 7) << 4));
}

// ---------------------------------------------------------------------------
// Kernel 1: gates (validated round 1/2).
// ---------------------------------------------------------------------------
__global__ __launch_bounds__(64) void gates_kernel(
    const float* __restrict__ q, const float* __restrict__ k, const float* __restrict__ v,
    const float* __restrict__ Wi, const float* __restrict__ bi,
    const float* __restrict__ Wf, const float* __restrict__ bf,
    float* __restrict__ ig_ws, float* __restrict__ lf_ws) {
  const int lane = threadIdx.x;
  const int g0 = blockIdx.x * 4;
  const int b  = g0 >> 11;
  const int t0 = g0 & (SS - 1);

  float acc[64];
  #pragma unroll
  for (int i = 0; i < 64; ++i) acc[i] = 0.f;

  const float* rowq = q + (size_t)b * SS * DD + (size_t)t0 * DD;
  const float* rowk = k + (size_t)b * SS * DD + (size_t)t0 * DD;
  const float* rowv = v + (size_t)b * SS * DD + (size_t)t0 * DD;

  #pragma unroll 1
  for (int u4 = 0; u4 < 12; ++u4) {
    const int e4  = lane + 64 * u4;
    const int seg = e4 >> 8;
    const int off = (e4 & 255) << 2;
    const float* base = (seg == 0) ? rowq : (seg == 1) ? rowk : rowv;
    float4 a0 = *(const float4*)(base + off);
    float4 a1 = *(const float4*)(base + DD + off);
    float4 a2 = *(const float4*)(base + 2 * DD + off);
    float4 a3 = *(const float4*)(base + 3 * DD + off);
    const int ew = e4 * 4 * NHD;
    #pragma unroll
    for (int ee = 0; ee < 4; ++ee) {
      float4 wiA = *(const float4*)(Wi + ew + ee * NHD);
      float4 wiB = *(const float4*)(Wi + ew + ee * NHD + 4);
      float4 wfA = *(const float4*)(Wf + ew + ee * NHD);
      float4 wfB = *(const float4*)(Wf + ew + ee * NHD + 4);
      float w16[16] = {wiA.x, wiA.y, wiA.z, wiA.w, wiB.x, wiB.y, wiB.z, wiB.w,
                       wfA.x, wfA.y, wfA.z, wfA.w, wfB.x, wfB.y, wfB.z, wfB.w};
      float av[4];
      av[0] = (ee == 0) ? a0.x : (ee == 1) ? a0.y : (ee == 2) ? a0.z : a0.w;
      av[1] = (ee == 0) ? a1.x : (ee == 1) ? a1.y : (ee == 2) ? a1.z : a1.w;
      av[2] = (ee == 0) ? a2.x : (ee == 1) ? a2.y : (ee == 2) ? a2.z : a2.w;
      av[3] = (ee == 0) ? a3.x : (ee == 1) ? a3.y : (ee == 2) ? a3.z : a3.w;
      #pragma unroll
      for (int r = 0; r < 4; ++r) {
        #pragma unroll
        for (int cc = 0; cc < 16; ++cc)
          acc[r * 16 + cc] = fmaf(av[r], w16[cc], acc[r * 16 + cc]);
      }
    }
  }

  __shared__ float lds[64 * 65];
  #pragma unroll
  for (int x = 0; x < 64; ++x) lds[x * 65 + lane] = acc[x];
  __syncthreads();
  float s = 0.f;
  #pragma unroll 4
  for (int l = 0; l < 64; ++l) s += lds[lane * 65 + l];

  const int r  = lane >> 4;
  const int gi = lane & 15;
  const int t  = t0 + r;
  if (gi < 8) {
    ig_ws[(size_t)(b * NHD + gi) * SS + t] = s + bi[gi];
  } else {
    const int hh = gi - 8;
    float ft = s + bf[hh];
    float lf = fminf(ft, 0.f) - log1pf(expf(-fabsf(ft)));
    lf_ws[(size_t)(b * NHD + hh) * SS + t] = lf;
  }
}

// ---------------------------------------------------------------------------
// Kernel 2: prep (validated).
// ---------------------------------------------------------------------------
__global__ __launch_bounds__(128) void prep_kernel(float* __restrict__ ws,
                                                   const float* __restrict__ m0,
                                                   float* __restrict__ out) {
  const int bh = blockIdx.x;
  const int s  = threadIdx.x;
  __shared__ float sh[128];
  __shared__ float bc2[2];
  __shared__ float mina[NC], mxga[NC], lfsa[NC];
  const float* lf = ws + OFF_LF + (size_t)bh * SS;
  const float* ig = ws + OFF_IG + (size_t)bh * SS;
  const float m0v = m0[bh];
  float m_run = m0v, LFtot = 0.f;
  for (int g = 0; g < NC; ++g) {
    const int t = g * CL + s;
    float lfv = lf[t], iv = ig[t];
    float v = lfv;
    sh[s] = v; __syncthreads();
    for (int off = 1; off < 128; off <<= 1) {
      float tv = (s >= off) ? sh[s - off] : 0.f;
      __syncthreads();
      v += tv; sh[s] = v; __syncthreads();
    }
    float Bv = v;
    float Gv = iv - Bv;
    v = Gv; sh[s] = v; __syncthreads();
    for (int off = 1; off < 128; off <<= 1) {
      float tv = (s >= off) ? sh[s - off] : -3.0e38f;
      __syncthreads();
      v = fmaxf(v, tv); sh[s] = v; __syncthreads();
    }
    float Rv = v;
    if (s == 127) { bc2[0] = Bv; bc2[1] = Rv; }
    __syncthreads();
    float Bend = bc2[0], mxG = bc2[1];
    __syncthreads();
    ws[OFF_B  + (size_t)bh * SS + t] = Bv;
    ws[OFF_G  + (size_t)bh * SS + t] = Gv;
    ws[OFF_RM + (size_t)bh * SS + t] = fmaxf(m_run, Rv);
    ws[OFF_E  + (size_t)bh * SS + t] = expf(Gv - mxG);
    if (s == 0) {
      ws[OFF_MIN + bh * NC + g] = m_run;
      mina[g] = m_run; mxga[g] = mxG; lfsa[g] = LFtot;
    }
    m_run = Bend + fmaxf(m_run, mxG);
    LFtot += Bend;
  }
  if (s == 0) {
    out[OUT_M + bh] = m_run;
    float* sc = ws + OFF_SC + bh * 80;
    float S = -3.0e38f;
    for (int g = 0; g < NC; ++g) {
      float r_g = lfsa[g] - mina[g];
      sc[g]      = expf(S + r_g);
      sc[20 + g] = expf(m0v + lfsa[g] - mina[g]);
      float s_g = mxga[g] - lfsa[g];
      float Sn = fmaxf(S, s_g);
      sc[40 + g] = expf(S - Sn);
      sc[60 + g] = expf(s_g - Sn);
      S = Sn;
    }
    float r16 = LFtot - m_run;
    sc[16] = expf(S + r16);
    sc[36] = expf(m0v + LFtot - m_run);
  }
}

// ---------------------------------------------------------------------------
// Kernel 3: U^(g) = sum_r E_r * k̂_r v_r^T  (validated).
// ---------------------------------------------------------------------------
__global__ __launch_bounds__(64) void u_kernel(const float* __restrict__ k,
                                               const float* __restrict__ v,
                                               float* __restrict__ ws) {
  const int lane = threadIdx.x;
  const int jt = blockIdx.x & 15;
  const int g  = (blockIdx.x >> 4) & 15;
  const int bh = blockIdx.x >> 8;
  const int b = bh >> 3, hh = bh & 7;
  const int j  = jt * 8 + (lane >> 3);
  const int i0 = (lane & 7) * 16;
  const size_t headoff = (size_t)b * SS * DD + (size_t)hh * SS * DHD;
  const float* kb = k + headoff + (size_t)g * CL * DHD;
  const float* vb = v + headoff + (size_t)g * CL * DHD;
  const float* E  = ws + OFF_E + (size_t)bh * SS + g * CL;
  float acc[16];
  #pragma unroll
  for (int u = 0; u < 16; ++u) acc[u] = 0.f;
  #pragma unroll 2
  for (int r = 0; r < CL; ++r) {
    float ev = E[r] * SCALE * vb[(size_t)r * DHD + j];
    const float* kr = kb + (size_t)r * DHD + i0;
    float4 k0 = *(const float4*)(kr);
    float4 k1 = *(const float4*)(kr + 4);
    float4 k2 = *(const float4*)(kr + 8);
    float4 k3 = *(const float4*)(kr + 12);
    acc[0]  += ev * k0.x; acc[1]  += ev * k0.y; acc[2]  += ev * k0.z; acc[3]  += ev * k0.w;
    acc[4]  += ev * k1.x; acc[5]  += ev * k1.y; acc[6]  += ev * k1.z; acc[7]  += ev * k1.w;
    acc[8]  += ev * k2.x; acc[9]  += ev * k2.y; acc[10] += ev * k2.z; acc[11] += ev * k2.w;
    acc[12] += ev * k3.x; acc[13] += ev * k3.y; acc[14] += ev * k3.z; acc[15] += ev * k3.w;
  }
  float* Ubuf = ws + OFF_U + (size_t)(bh * NC + g) * (DHD * DHD);
  #pragma unroll
  for (int u = 0; u < 16; ++u) Ubuf[(size_t)(i0 + u) * DHD + j] = acc[u];
}

__global__ __launch_bounds__(128) void un_kernel(const float* __restrict__ k,
                                                 float* __restrict__ ws) {
  const int i = threadIdx.x;
  const int g = blockIdx.x & 15;
  const int bh = blockIdx.x >> 4;
  const int b = bh >> 3, hh = bh & 7;
  const float* kb = k + (size_t)b * SS * DD + (size_t)hh * SS * DHD + (size_t)g * CL * DHD;
  const float* E = ws + OFF_E + (size_t)bh * SS + g * CL;
  float acc = 0.f;
  #pragma unroll 4
  for (int r = 0; r < CL; ++r) acc += E[r] * SCALE * kb[(size_t)r * DHD + i];
  ws[OFF_UN + (size_t)(bh * NC + g) * DHD + i] = acc;
}

// ---------------------------------------------------------------------------
// Kernel 4: prefix combine (validated).
// ---------------------------------------------------------------------------
__global__ __launch_bounds__(256) void cprefix_kernel(const float* __restrict__ c0,
                                                      float* __restrict__ ws,
                                                      float* __restrict__ out) {
  const int bh = blockIdx.x >> 6;
  const int elem = ((blockIdx.x & 63) << 8) + threadIdx.x;
  const float* sc = ws + OFF_SC + bh * 80;
  float c0v = c0[(size_t)bh * 16384 + elem];
  float* Ub = ws + OFF_U + (size_t)bh * NC * 16384 + elem;
  float P = 0.f;
  #pragma unroll 1
  for (int g = 0; g < NC; ++g) {
    float u = Ub[(size_t)g * 16384];
    Ub[(size_t)g * 16384] = sc[g] * P + sc[20 + g] * c0v;
    P = sc[40 + g] * P + sc[60 + g] * u;
  }
  out[OUT_C + (size_t)bh * 16384 + elem] = sc[16] * P + sc[36] * c0v;
}

__global__ __launch_bounds__(128) void nprefix_kernel(const float* __restrict__ n0,
                                                      float* __restrict__ ws,
                                                      float* __restrict__ out) {
  const int bh = blockIdx.x;
  const int i = threadIdx.x;
  const float* sc = ws + OFF_SC + bh * 80;
  float n0v = n0[bh * DHD + i];
  const float* Ub = ws + OFF_UN + (size_t)bh * NC * DHD + i;
  float* Nb = ws + OFF_NIN + (size_t)bh * NC * DHD + i;
  float P = 0.f;
  #pragma unroll 1
  for (int g = 0; g < NC; ++g) {
    float u = Ub[g * DHD];
    Nb[g * DHD] = sc[g] * P + sc[20 + g] * n0v;
    P = sc[40 + g] * P + sc[60 + g] * u;
  }
  out[OUT_N + bh * DHD + i] = sc[16] * P + sc[36] * n0v;
}

// ---------------------------------------------------------------------------
// Kernel 5: MFMA (fp16 operands, fp32 accum) intra-chunk attention + inter
// + denom + fused LN.  One block per (bh, chunk); 4 waves; wave w owns
// s-tiles {w, w+4}.  LDS: P[128][128]f16 swz | stage[128][128]f16 swz | scalars.
// ---------------------------------------------------------------------------
__global__ __launch_bounds__(256, 2) void intra_kernel(
    const float* __restrict__ q, const float* __restrict__ k, const float* __restrict__ v,
    const float* __restrict__ lnw, float* __restrict__ ws, float* __restrict__ out) {
  extern __shared__ char smem[];
  char* Plds  = smem;
  char* stage = smem + 32768;
  float* Gs   = (float*)(smem + 65536);
  float* Msd  = Gs + 128;
  float* Bsd  = Gs + 256;
  float* alph = Gs + 384;
  float* ninS = Gs + 512;
  float* qnS  = Gs + 640;

  const int tid = threadIdx.x;
  const int wid = tid >> 6;
  const int lane = tid & 63;
  const int g16 = lane >> 4;
  const int l15 = lane & 15;
  const int g = blockIdx.x & 15;
  const int bh = blockIdx.x >> 4;
  const int b = bh >> 3, hh = bh & 7;
  const int t0 = g * CL;

  const size_t headoff = (size_t)b * SS * DD + (size_t)hh * SS * DHD;
  const float* qb = q + headoff;
  const float* kb = k + headoff;
  const float* vb = v + headoff;
  const float m_in = ws[OFF_MIN + bh * NC + g];

  if (tid < 128) {
    float M = ws[OFF_RM + (size_t)bh * SS + t0 + tid];
    Msd[tid] = M;
    alph[tid] = __expf(m_in - M);
    Gs[tid]  = ws[OFF_G + (size_t)bh * SS + t0 + tid];
    Bsd[tid] = ws[OFF_B + (size_t)bh * SS + t0 + tid];
    ninS[tid] = ws[OFF_NIN + (size_t)(bh * NC + g) * DHD + tid];
  }
  __syncthreads();

  const int st[2] = {wid, wid + 4};

  // transpose-stage a [128][128] fp32 row-major matrix into `stage` as f16 [col][row]
  auto stageT = [&](const float* src) {
    #pragma unroll 4
    for (int it = 0; it < 16; ++it) {
      const int idx = (it << 8) + tid;
      const int j = idx & 127;
      const int r0 = (idx >> 7) << 2;
      float a0 = src[(size_t)r0 * DHD + j];
      float a1 = src[(size_t)(r0 + 1) * DHD + j];
      float a2 = src[(size_t)(r0 + 2) * DHD + j];
      float a3 = src[(size_t)(r0 + 3) * DHD + j];
      *(uint2*)swp(stage, j, r0 * 2) = make_uint2(pk2h(a0, a1), pk2h(a2, a3));
    }
  };

  // ---- phase A: Q fragments (B-operand in S-phase, A-operand in QC) + qn2 ----
  f16x8 qf[2][4];
  float qn2[2];
  #pragma unroll
  for (int idx = 0; idx < 2; ++idx) {
    const float* qrow = qb + (size_t)(t0 + st[idx] * 16 + l15) * DHD + g16 * 8;
    float p = 0.f;
    #pragma unroll
    for (int kst = 0; kst < 4; ++kst) {
      float4 a = *(const float4*)(qrow + kst * 32);
      float4 c = *(const float4*)(qrow + kst * 32 + 4);
      qf[idx][kst] = mkfrag(a, c);
      const float* nn = &ninS[kst * 32 + g16 * 8];
      p += a.x * nn[0] + a.y * nn[1] + a.z * nn[2] + a.w * nn[3]
         + c.x * nn[4] + c.y * nn[5] + c.z * nn[6] + c.w * nn[7];
    }
    p += __shfl_xor(p, 16); p += __shfl_xor(p, 32);
    qn2[idx] = p;
  }

  // ---- stage Cin^T (f16) ----
  stageT(ws + OFF_U + (size_t)(bh * NC + g) * (DHD * DHD));
  __syncthreads();

  // ---- QC: acc = Q @ Cin ----
  f32x4 acc[2][8];
  #pragma unroll
  for (int jt = 0; jt < 8; ++jt) {
    f32x4 a0 = {0.f, 0.f, 0.f, 0.f}, a1 = {0.f, 0.f, 0.f, 0.f};
    #pragma unroll
    for (int kst = 0; kst < 4; ++kst) {
      f16x8 bfr = *(f16x8*)swp(stage, jt * 16 + l15, (kst * 32 + g16 * 8) * 2);
      a0 = __builtin_amdgcn_mfma_f32_16x16x32_f16(qf[0][kst], bfr, a0, 0, 0, 0);
      a1 = __builtin_amdgcn_mfma_f32_16x16x32_f16(qf[1][kst], bfr, a1, 0, 0, 0);
    }
    acc[0][jt] = a0; acc[1][jt] = a1;
  }
  // alpha scale (row s = st*16 + g16*4 + reg)
  #pragma unroll
  for (int idx = 0; idx < 2; ++idx) {
    float4 av = *(const float4*)&alph[st[idx] * 16 + g16 * 4];
    #pragma unroll
    for (int jt = 0; jt < 8; ++jt) {
      acc[idx][jt][0] *= av.x; acc[idx][jt][1] *= av.y;
      acc[idx][jt][2] *= av.z; acc[idx][jt][3] *= av.w;
    }
  }
  __syncthreads();

  // ---- stage V^T (f16) over the same region ----
  stageT(vb + (size_t)t0 * DHD);

  // ---- S-phase: S^T tiles = mfma(K, Q); weight; write P (f16, swz) ----
  float qns[2] = {0.f, 0.f};
  const int rtmax = st[1] | 1;
  #pragma unroll 1
  for (int rt = 0; rt <= rtmax; ++rt) {
    f16x8 kf[4];
    const float* krow = kb + (size_t)(t0 + rt * 16 + l15) * DHD + g16 * 8;
    #pragma unroll
    for (int kst = 0; kst < 4; ++kst)
      kf[kst] = mkfrag(*(const float4*)(krow + kst * 32),
                       *(const float4*)(krow + kst * 32 + 4));
    float4 Gq = *(const float4*)&Gs[rt * 16 + g16 * 4];
    const float* Gqe = (const float*)&Gq;
    #pragma unroll
    for (int idx = 0; idx < 2; ++idx) {
      if (rt > (st[idx] | 1)) continue;
      f32x4 sa = {0.f, 0.f, 0.f, 0.f};
      #pragma unroll
      for (int kst = 0; kst < 4; ++kst)
        sa = __builtin_amdgcn_mfma_f32_16x16x32_f16(kf[kst], qf[idx][kst], sa, 0, 0, 0);
      const int s = st[idx] * 16 + l15;
      const float Ms = Msd[s];
      float vr[4];
      #pragma unroll
      for (int rr = 0; rr < 4; ++rr) {
        const int r = rt * 16 + g16 * 4 + rr;
        float w = (r <= s) ? __expf(Gqe[rr] - Ms) * SCALE : 0.f;
        vr[rr] = sa[rr] * w;
      }
      qns[idx] += vr[0] + vr[1] + vr[2] + vr[3];
      *(uint2*)swp(Plds, s, (rt * 16 + g16 * 4) * 2) =
          make_uint2(pk2h(vr[0], vr[1]), pk2h(vr[2], vr[3]));
    }
  }
  #pragma unroll
  for (int idx = 0; idx < 2; ++idx) {
    float p = qns[idx];
    p += __shfl_xor(p, 16); p += __shfl_xor(p, 32);
    if (g16 == 0) {
      const int s = st[idx] * 16 + l15;
      qnS[s] = p + alph[s] * qn2[idx];
    }
  }
  __syncthreads();

  // ---- PV: acc += P @ V ----
  const int kmax0 = ((st[0] | 1) + 1) >> 1;
  const int kmax1 = ((st[1] | 1) + 1) >> 1;
  #pragma unroll
  for (int kst = 0; kst < 4; ++kst) {
    if (kst < kmax1) {
      f16x8 vf[8];
      #pragma unroll
      for (int jt = 0; jt < 8; ++jt)
        vf[jt] = *(f16x8*)swp(stage, jt * 16 + l15, (kst * 32 + g16 * 8) * 2);
      if (kst < kmax0) {
        f16x8 pf = *(f16x8*)swp(Plds, st[0] * 16 + l15, (kst * 32 + g16 * 8) * 2);
        #pragma unroll
        for (int jt = 0; jt < 8; ++jt)
          acc[0][jt] = __builtin_amdgcn_mfma_f32_16x16x32_f16(pf, vf[jt], acc[0][jt], 0, 0, 0);
      }
      {
        f16x8 pf = *(f16x8*)swp(Plds, st[1] * 16 + l15, (kst * 32 + g16 * 8) * 2);
        #pragma unroll
        for (int jt = 0; jt < 8; ++jt)
          acc[1][jt] = __builtin_amdgcn_mfma_f32_16x16x32_f16(pf, vf[jt], acc[1][jt], 0, 0, 0);
      }
    }
  }

  // ---- epilogue: denom, LayerNorm, store ----
  const float* lw = lnw + hh * DHD;
  float lwv[8];
  #pragma unroll
  for (int jt = 0; jt < 8; ++jt) lwv[jt] = lw[jt * 16 + l15];

  #pragma unroll
  for (int idx = 0; idx < 2; ++idx) {
    const int s0 = st[idx] * 16 + g16 * 4;
    float4 qnq = *(const float4*)&qnS[s0];
    float4 Bq  = *(const float4*)&Bsd[s0];
    float4 Mq  = *(const float4*)&Msd[s0];
    const float* qne = (const float*)&qnq;
    const float* Be  = (const float*)&Bq;
    const float* Me  = (const float*)&Mq;
    #pragma unroll
    for (int reg = 0; reg < 4; ++reg) {
      float den = fmaxf(fabsf(qne[reg]), __expf(-(Be[reg] + Me[reg]))) + 1e-6f;
      float inv = 1.0f / den;
      float mp = 0.f, sp = 0.f;
      float hv[8];
      #pragma unroll
      for (int jt = 0; jt < 8; ++jt) {
        float h = acc[idx][jt][reg] * inv;
        hv[jt] = h;
        mp += h; sp += h * h;
      }
      mp += __shfl_xor(mp, 1); sp += __shfl_xor(sp, 1);
      mp += __shfl_xor(mp, 2); sp += __shfl_xor(sp, 2);
      mp += __shfl_xor(mp, 4); sp += __shfl_xor(sp, 4);
      mp += __shfl_xor(mp, 8); sp += __shfl_xor(sp, 8);
      float mu = mp * (1.f / 128.f);
      float var = fmaxf(sp * (1.f / 128.f) - mu * mu, 0.f);
      float rstd = rsqrtf(var + 1e-6f);
      float* orow = out + (size_t)(b * SS + t0 + s0 + reg) * DD + hh * DHD;
      #pragma unroll
      for (int jt = 0; jt < 8; ++jt)
        orow[jt * 16 + l15] = (hv[jt] - mu) * rstd * lwv[jt];
    }
  }
}

extern "C" void kernel_launch(void* const* d_in, const int* in_sizes, int n_in,
                              void* d_out, int out_size, void* d_ws, size_t ws_size,
                              hipStream_t stream) {
  const float* q   = (const float*)d_in[0];
  const float* k   = (const float*)d_in[1];
  const float* v   = (const float*)d_in[2];
  const float* c0  = (const float*)d_in[3];
  const float* n0  = (const float*)d_in[4];
  const float* m0  = (const float*)d_in[5];
  const float* Wi  = (const float*)d_in[6];
  const float* bi  = (const float*)d_in[7];
  const float* Wf  = (const float*)d_in[8];
  const float* bf  = (const float*)d_in[9];
  const float* lnw = (const float*)d_in[10];
  float* out = (float*)d_out;
  float* ws  = (float*)d_ws;

  gates_kernel<<<BB * SS / 4, 64, 0, stream>>>(q, k, v, Wi, bi, Wf, bf,
                                               ws + OFF_IG, ws + OFF_LF);
  prep_kernel<<<BB * NHD, 128, 0, stream>>>(ws, m0, out);
  u_kernel<<<BB * NHD * NC * 16, 64, 0, stream>>>(k, v, ws);
  un_kernel<<<BB * NHD * NC, 128, 0, stream>>>(k, ws);
  cprefix_kernel<<<BB * NHD * 64, 256, 0, stream>>>(c0, ws, out);
  nprefix_kernel<<<BB * NHD, 128, 0, stream>>>(n0, ws, out);
  intra_kernel<<<BB * NHD * NC, 256, 69632, stream>>>(q, k, v, lnw, ws, out);
}

// Round 5
// 164.687 us; speedup vs baseline: 6.2944x; 2.3724x over previous
//
#include <hip/hip_runtime.h>
#include <math.h>

#define BB 4
#define SS 2048
#define DD 1024
#define NHD 8
#define DHD 128
#define NC 16
#define CL 128
#define SCALE 0.08838834764831845f

// workspace offsets (in floats)
#define OFF_IG   0
#define OFF_LF   65536
#define OFF_B    131072
#define OFF_G    196608
#define OFF_E    262144
#define OFF_RM   327680
#define OFF_MIN  393216
#define OFF_SC   393728
#define OFF_UN   396288
#define OFF_NIN  461824
#define OFF_U    527360
// out offsets (floats)
#define OUT_C  8388608
#define OUT_N  8912896
#define OUT_M  8916992

typedef __attribute__((ext_vector_type(8))) _Float16 f16x8;
typedef __attribute__((ext_vector_type(4))) float f32x4;

__device__ __forceinline__ unsigned pk2h(float a, float b) {
  union { _Float16 h[2]; unsigned u; } f;
  f.h[0] = (_Float16)a; f.h[1] = (_Float16)b;
  return f.u;
}
__device__ __forceinline__ f16x8 mkfrag(float4 a, float4 c) {
  f16x8 f;
  f[0] = (_Float16)a.x; f[1] = (_Float16)a.y; f[2] = (_Float16)a.z; f[3] = (_Float16)a.w;
  f[4] = (_Float16)c.x; f[5] = (_Float16)c.y; f[6] = (_Float16)c.z; f[7] = (_Float16)c.w;
  return f;
}
// 256B rows, XOR-swizzle byte bits 4..6 with row&7 (m214 attn recipe)
__device__ __forceinline__ char* swp(char* base, int row, int byte) {
  return base + (((row << 8) + byte) ^ ((row & 7) << 4));
}

// ---------------------------------------------------------------------------
// Kernel 1: gates (validated round 1/2).
// ---------------------------------------------------------------------------
__global__ __launch_bounds__(64) void gates_kernel(
    const float* __restrict__ q, const float* __restrict__ k, const float* __restrict__ v,
    const float* __restrict__ Wi, const float* __restrict__ bi,
    const float* __restrict__ Wf, const float* __restrict__ bf,
    float* __restrict__ ig_ws, float* __restrict__ lf_ws) {
  const int lane = threadIdx.x;
  const int g0 = blockIdx.x * 4;
  const int b  = g0 >> 11;
  const int t0 = g0 & (SS - 1);

  float acc[64];
  #pragma unroll
  for (int i = 0; i < 64; ++i) acc[i] = 0.f;

  const float* rowq = q + (size_t)b * SS * DD + (size_t)t0 * DD;
  const float* rowk = k + (size_t)b * SS * DD + (size_t)t0 * DD;
  const float* rowv = v + (size_t)b * SS * DD + (size_t)t0 * DD;

  #pragma unroll 1
  for (int u4 = 0; u4 < 12; ++u4) {
    const int e4  = lane + 64 * u4;
    const int seg = e4 >> 8;
    const int off = (e4 & 255) << 2;
    const float* base = (seg == 0) ? rowq : (seg == 1) ? rowk : rowv;
    float4 a0 = *(const float4*)(base + off);
    float4 a1 = *(const float4*)(base + DD + off);
    float4 a2 = *(const float4*)(base + 2 * DD + off);
    float4 a3 = *(const float4*)(base + 3 * DD + off);
    const int ew = e4 * 4 * NHD;
    #pragma unroll
    for (int ee = 0; ee < 4; ++ee) {
      float4 wiA = *(const float4*)(Wi + ew + ee * NHD);
      float4 wiB = *(const float4*)(Wi + ew + ee * NHD + 4);
      float4 wfA = *(const float4*)(Wf + ew + ee * NHD);
      float4 wfB = *(const float4*)(Wf + ew + ee * NHD + 4);
      float w16[16] = {wiA.x, wiA.y, wiA.z, wiA.w, wiB.x, wiB.y, wiB.z, wiB.w,
                       wfA.x, wfA.y, wfA.z, wfA.w, wfB.x, wfB.y, wfB.z, wfB.w};
      float av[4];
      av[0] = (ee == 0) ? a0.x : (ee == 1) ? a0.y : (ee == 2) ? a0.z : a0.w;
      av[1] = (ee == 0) ? a1.x : (ee == 1) ? a1.y : (ee == 2) ? a1.z : a1.w;
      av[2] = (ee == 0) ? a2.x : (ee == 1) ? a2.y : (ee == 2) ? a2.z : a2.w;
      av[3] = (ee == 0) ? a3.x : (ee == 1) ? a3.y : (ee == 2) ? a3.z : a3.w;
      #pragma unroll
      for (int r = 0; r < 4; ++r) {
        #pragma unroll
        for (int cc = 0; cc < 16; ++cc)
          acc[r * 16 + cc] = fmaf(av[r], w16[cc], acc[r * 16 + cc]);
      }
    }
  }

  __shared__ float lds[64 * 65];
  #pragma unroll
  for (int x = 0; x < 64; ++x) lds[x * 65 + lane] = acc[x];
  __syncthreads();
  float s = 0.f;
  #pragma unroll 4
  for (int l = 0; l < 64; ++l) s += lds[lane * 65 + l];

  const int r  = lane >> 4;
  const int gi = lane & 15;
  const int t  = t0 + r;
  if (gi < 8) {
    ig_ws[(size_t)(b * NHD + gi) * SS + t] = s + bi[gi];
  } else {
    const int hh = gi - 8;
    float ft = s + bf[hh];
    float lf = fminf(ft, 0.f) - log1pf(expf(-fabsf(ft)));
    lf_ws[(size_t)(b * NHD + hh) * SS + t] = lf;
  }
}

// ---------------------------------------------------------------------------
// Kernel 2: prep (validated).
// ---------------------------------------------------------------------------
__global__ __launch_bounds__(128) void prep_kernel(float* __restrict__ ws,
                                                   const float* __restrict__ m0,
                                                   float* __restrict__ out) {
  const int bh = blockIdx.x;
  const int s  = threadIdx.x;
  __shared__ float sh[128];
  __shared__ float bc2[2];
  __shared__ float mina[NC], mxga[NC], lfsa[NC];
  const float* lf = ws + OFF_LF + (size_t)bh * SS;
  const float* ig = ws + OFF_IG + (size_t)bh * SS;
  const float m0v = m0[bh];
  float m_run = m0v, LFtot = 0.f;
  for (int g = 0; g < NC; ++g) {
    const int t = g * CL + s;
    float lfv = lf[t], iv = ig[t];
    float v = lfv;
    sh[s] = v; __syncthreads();
    for (int off = 1; off < 128; off <<= 1) {
      float tv = (s >= off) ? sh[s - off] : 0.f;
      __syncthreads();
      v += tv; sh[s] = v; __syncthreads();
    }
    float Bv = v;
    float Gv = iv - Bv;
    v = Gv; sh[s] = v; __syncthreads();
    for (int off = 1; off < 128; off <<= 1) {
      float tv = (s >= off) ? sh[s - off] : -3.0e38f;
      __syncthreads();
      v = fmaxf(v, tv); sh[s] = v; __syncthreads();
    }
    float Rv = v;
    if (s == 127) { bc2[0] = Bv; bc2[1] = Rv; }
    __syncthreads();
    float Bend = bc2[0], mxG = bc2[1];
    __syncthreads();
    ws[OFF_B  + (size_t)bh * SS + t] = Bv;
    ws[OFF_G  + (size_t)bh * SS + t] = Gv;
    ws[OFF_RM + (size_t)bh * SS + t] = fmaxf(m_run, Rv);
    ws[OFF_E  + (size_t)bh * SS + t] = expf(Gv - mxG);
    if (s == 0) {
      ws[OFF_MIN + bh * NC + g] = m_run;
      mina[g] = m_run; mxga[g] = mxG; lfsa[g] = LFtot;
    }
    m_run = Bend + fmaxf(m_run, mxG);
    LFtot += Bend;
  }
  if (s == 0) {
    out[OUT_M + bh] = m_run;
    float* sc = ws + OFF_SC + bh * 80;
    float S = -3.0e38f;
    for (int g = 0; g < NC; ++g) {
      float r_g = lfsa[g] - mina[g];
      sc[g]      = expf(S + r_g);
      sc[20 + g] = expf(m0v + lfsa[g] - mina[g]);
      float s_g = mxga[g] - lfsa[g];
      float Sn = fmaxf(S, s_g);
      sc[40 + g] = expf(S - Sn);
      sc[60 + g] = expf(s_g - Sn);
      S = Sn;
    }
    float r16 = LFtot - m_run;
    sc[16] = expf(S + r16);
    sc[36] = expf(m0v + LFtot - m_run);
  }
}

// ---------------------------------------------------------------------------
// Kernel 3 (NEW): MFMA U^(g) = K̂ᵀ·diag(E)·V  + fused Un row-sums.
// One block per (bh,g); 4 waves; wave w owns i-tiles {2w,2w+1} × all j-tiles.
// LDS: Kt[i][r] f16 swz (E·scale folded in) | Vt[j][r] f16 swz.
// ---------------------------------------------------------------------------
__global__ __launch_bounds__(256, 2) void u_kernel(const float* __restrict__ k,
                                                   const float* __restrict__ v,
                                                   float* __restrict__ ws) {
  extern __shared__ char smem[];
  char* Kt = smem;
  char* Vt = smem + 32768;

  const int tid = threadIdx.x;
  const int wid = tid >> 6;
  const int lane = tid & 63;
  const int g16 = lane >> 4;
  const int l15 = lane & 15;
  const int g  = blockIdx.x & 15;
  const int bh = blockIdx.x >> 4;
  const int b = bh >> 3, hh = bh & 7;
  const size_t headoff = (size_t)b * SS * DD + (size_t)hh * SS * DHD;
  const float* kb = k + headoff + (size_t)g * CL * DHD;
  const float* vb = v + headoff + (size_t)g * CL * DHD;
  const float* E  = ws + OFF_E + (size_t)bh * SS + g * CL;

  // stage: thread handles column c, rows r0..r0+3 (coalesced along c)
  #pragma unroll 4
  for (int it = 0; it < 16; ++it) {
    const int idx = (it << 8) + tid;
    const int c  = idx & 127;
    const int r0 = (idx >> 7) << 2;
    float e0 = E[r0] * SCALE, e1 = E[r0 + 1] * SCALE,
          e2 = E[r0 + 2] * SCALE, e3 = E[r0 + 3] * SCALE;
    float a0 = kb[(size_t)r0 * DHD + c] * e0;
    float a1 = kb[(size_t)(r0 + 1) * DHD + c] * e1;
    float a2 = kb[(size_t)(r0 + 2) * DHD + c] * e2;
    float a3 = kb[(size_t)(r0 + 3) * DHD + c] * e3;
    *(uint2*)swp(Kt, c, r0 * 2) = make_uint2(pk2h(a0, a1), pk2h(a2, a3));
    float b0 = vb[(size_t)r0 * DHD + c];
    float b1 = vb[(size_t)(r0 + 1) * DHD + c];
    float b2 = vb[(size_t)(r0 + 2) * DHD + c];
    float b3 = vb[(size_t)(r0 + 3) * DHD + c];
    *(uint2*)swp(Vt, c, r0 * 2) = make_uint2(pk2h(b0, b1), pk2h(b2, b3));
  }
  __syncthreads();

  // fused Un[i] = sum_r Kt[i][r] (E·scale already folded)
  if (tid < 128) {
    float s = 0.f;
    #pragma unroll
    for (int r8 = 0; r8 < 16; ++r8) {
      f16x8 x = *(f16x8*)swp(Kt, tid, r8 * 16);
      s += (float)x[0] + (float)x[1] + (float)x[2] + (float)x[3]
         + (float)x[4] + (float)x[5] + (float)x[6] + (float)x[7];
    }
    ws[OFF_UN + (size_t)(bh * NC + g) * DHD + tid] = s;
  }

  // MFMA: U[i][j] = sum_r Kt[i][r] * Vt[j][r]
  float* Ubuf = ws + OFF_U + (size_t)(bh * NC + g) * (DHD * DHD);
  const int it0 = wid * 2;
  #pragma unroll 1
  for (int jt = 0; jt < 8; ++jt) {
    f32x4 a0 = {0.f, 0.f, 0.f, 0.f}, a1 = {0.f, 0.f, 0.f, 0.f};
    #pragma unroll
    for (int kst = 0; kst < 4; ++kst) {
      const int byte = (kst * 32 + g16 * 8) * 2;
      f16x8 bf0 = *(f16x8*)swp(Vt, jt * 16 + l15, byte);
      f16x8 af0 = *(f16x8*)swp(Kt, it0 * 16 + l15, byte);
      f16x8 af1 = *(f16x8*)swp(Kt, (it0 + 1) * 16 + l15, byte);
      a0 = __builtin_amdgcn_mfma_f32_16x16x32_f16(af0, bf0, a0, 0, 0, 0);
      a1 = __builtin_amdgcn_mfma_f32_16x16x32_f16(af1, bf0, a1, 0, 0, 0);
    }
    // D layout: row = g16*4 + reg (within tile), col = l15
    #pragma unroll
    for (int reg = 0; reg < 4; ++reg) {
      Ubuf[(size_t)(it0 * 16 + g16 * 4 + reg) * DHD + jt * 16 + l15] = a0[reg];
      Ubuf[(size_t)((it0 + 1) * 16 + g16 * 4 + reg) * DHD + jt * 16 + l15] = a1[reg];
    }
  }
}

// ---------------------------------------------------------------------------
// Kernel 4: prefix combine (validated).
// ---------------------------------------------------------------------------
__global__ __launch_bounds__(256) void cprefix_kernel(const float* __restrict__ c0,
                                                      float* __restrict__ ws,
                                                      float* __restrict__ out) {
  const int bh = blockIdx.x >> 6;
  const int elem = ((blockIdx.x & 63) << 8) + threadIdx.x;
  const float* sc = ws + OFF_SC + bh * 80;
  float c0v = c0[(size_t)bh * 16384 + elem];
  float* Ub = ws + OFF_U + (size_t)bh * NC * 16384 + elem;
  float P = 0.f;
  #pragma unroll 1
  for (int g = 0; g < NC; ++g) {
    float u = Ub[(size_t)g * 16384];
    Ub[(size_t)g * 16384] = sc[g] * P + sc[20 + g] * c0v;
    P = sc[40 + g] * P + sc[60 + g] * u;
  }
  out[OUT_C + (size_t)bh * 16384 + elem] = sc[16] * P + sc[36] * c0v;
}

__global__ __launch_bounds__(128) void nprefix_kernel(const float* __restrict__ n0,
                                                      float* __restrict__ ws,
                                                      float* __restrict__ out) {
  const int bh = blockIdx.x;
  const int i = threadIdx.x;
  const float* sc = ws + OFF_SC + bh * 80;
  float n0v = n0[bh * DHD + i];
  const float* Ub = ws + OFF_UN + (size_t)bh * NC * DHD + i;
  float* Nb = ws + OFF_NIN + (size_t)bh * NC * DHD + i;
  float P = 0.f;
  #pragma unroll 1
  for (int g = 0; g < NC; ++g) {
    float u = Ub[g * DHD];
    Nb[g * DHD] = sc[g] * P + sc[20 + g] * n0v;
    P = sc[40 + g] * P + sc[60 + g] * u;
  }
  out[OUT_N + bh * DHD + i] = sc[16] * P + sc[36] * n0v;
}

// ---------------------------------------------------------------------------
// Kernel 5: MFMA (fp16 operands, fp32 accum) intra-chunk attention + inter
// + denom + fused LN (validated round 4).
// ---------------------------------------------------------------------------
__global__ __launch_bounds__(256, 2) void intra_kernel(
    const float* __restrict__ q, const float* __restrict__ k, const float* __restrict__ v,
    const float* __restrict__ lnw, float* __restrict__ ws, float* __restrict__ out) {
  extern __shared__ char smem[];
  char* Plds  = smem;
  char* stage = smem + 32768;
  float* Gs   = (float*)(smem + 65536);
  float* Msd  = Gs + 128;
  float* Bsd  = Gs + 256;
  float* alph = Gs + 384;
  float* ninS = Gs + 512;
  float* qnS  = Gs + 640;

  const int tid = threadIdx.x;
  const int wid = tid >> 6;
  const int lane = tid & 63;
  const int g16 = lane >> 4;
  const int l15 = lane & 15;
  const int g = blockIdx.x & 15;
  const int bh = blockIdx.x >> 4;
  const int b = bh >> 3, hh = bh & 7;
  const int t0 = g * CL;

  const size_t headoff = (size_t)b * SS * DD + (size_t)hh * SS * DHD;
  const float* qb = q + headoff;
  const float* kb = k + headoff;
  const float* vb = v + headoff;
  const float m_in = ws[OFF_MIN + bh * NC + g];

  if (tid < 128) {
    float M = ws[OFF_RM + (size_t)bh * SS + t0 + tid];
    Msd[tid] = M;
    alph[tid] = __expf(m_in - M);
    Gs[tid]  = ws[OFF_G + (size_t)bh * SS + t0 + tid];
    Bsd[tid] = ws[OFF_B + (size_t)bh * SS + t0 + tid];
    ninS[tid] = ws[OFF_NIN + (size_t)(bh * NC + g) * DHD + tid];
  }
  __syncthreads();

  const int st[2] = {wid, wid + 4};

  // transpose-stage a [128][128] fp32 row-major matrix into `stage` as f16 [col][row]
  auto stageT = [&](const float* src) {
    #pragma unroll 4
    for (int it = 0; it < 16; ++it) {
      const int idx = (it << 8) + tid;
      const int j = idx & 127;
      const int r0 = (idx >> 7) << 2;
      float a0 = src[(size_t)r0 * DHD + j];
      float a1 = src[(size_t)(r0 + 1) * DHD + j];
      float a2 = src[(size_t)(r0 + 2) * DHD + j];
      float a3 = src[(size_t)(r0 + 3) * DHD + j];
      *(uint2*)swp(stage, j, r0 * 2) = make_uint2(pk2h(a0, a1), pk2h(a2, a3));
    }
  };

  // ---- phase A: Q fragments (B-operand in S-phase, A-operand in QC) + qn2 ----
  f16x8 qf[2][4];
  float qn2[2];
  #pragma unroll
  for (int idx = 0; idx < 2; ++idx) {
    const float* qrow = qb + (size_t)(t0 + st[idx] * 16 + l15) * DHD + g16 * 8;
    float p = 0.f;
    #pragma unroll
    for (int kst = 0; kst < 4; ++kst) {
      float4 a = *(const float4*)(qrow + kst * 32);
      float4 c = *(const float4*)(qrow + kst * 32 + 4);
      qf[idx][kst] = mkfrag(a, c);
      const float* nn = &ninS[kst * 32 + g16 * 8];
      p += a.x * nn[0] + a.y * nn[1] + a.z * nn[2] + a.w * nn[3]
         + c.x * nn[4] + c.y * nn[5] + c.z * nn[6] + c.w * nn[7];
    }
    p += __shfl_xor(p, 16); p += __shfl_xor(p, 32);
    qn2[idx] = p;
  }

  // ---- stage Cin^T (f16) ----
  stageT(ws + OFF_U + (size_t)(bh * NC + g) * (DHD * DHD));
  __syncthreads();

  // ---- QC: acc = Q @ Cin ----
  f32x4 acc[2][8];
  #pragma unroll
  for (int jt = 0; jt < 8; ++jt) {
    f32x4 a0 = {0.f, 0.f, 0.f, 0.f}, a1 = {0.f, 0.f, 0.f, 0.f};
    #pragma unroll
    for (int kst = 0; kst < 4; ++kst) {
      f16x8 bfr = *(f16x8*)swp(stage, jt * 16 + l15, (kst * 32 + g16 * 8) * 2);
      a0 = __builtin_amdgcn_mfma_f32_16x16x32_f16(qf[0][kst], bfr, a0, 0, 0, 0);
      a1 = __builtin_amdgcn_mfma_f32_16x16x32_f16(qf[1][kst], bfr, a1, 0, 0, 0);
    }
    acc[0][jt] = a0; acc[1][jt] = a1;
  }
  // alpha scale (row s = st*16 + g16*4 + reg)
  #pragma unroll
  for (int idx = 0; idx < 2; ++idx) {
    float4 av = *(const float4*)&alph[st[idx] * 16 + g16 * 4];
    #pragma unroll
    for (int jt = 0; jt < 8; ++jt) {
      acc[idx][jt][0] *= av.x; acc[idx][jt][1] *= av.y;
      acc[idx][jt][2] *= av.z; acc[idx][jt][3] *= av.w;
    }
  }
  __syncthreads();

  // ---- stage V^T (f16) over the same region ----
  stageT(vb + (size_t)t0 * DHD);

  // ---- S-phase: S^T tiles = mfma(K, Q); weight; write P (f16, swz) ----
  float qns[2] = {0.f, 0.f};
  const int rtmax = st[1] | 1;
  #pragma unroll 1
  for (int rt = 0; rt <= rtmax; ++rt) {
    f16x8 kf[4];
    const float* krow = kb + (size_t)(t0 + rt * 16 + l15) * DHD + g16 * 8;
    #pragma unroll
    for (int kst = 0; kst < 4; ++kst)
      kf[kst] = mkfrag(*(const float4*)(krow + kst * 32),
                       *(const float4*)(krow + kst * 32 + 4));
    float4 Gq = *(const float4*)&Gs[rt * 16 + g16 * 4];
    const float* Gqe = (const float*)&Gq;
    #pragma unroll
    for (int idx = 0; idx < 2; ++idx) {
      if (rt > (st[idx] | 1)) continue;
      f32x4 sa = {0.f, 0.f, 0.f, 0.f};
      #pragma unroll
      for (int kst = 0; kst < 4; ++kst)
        sa = __builtin_amdgcn_mfma_f32_16x16x32_f16(kf[kst], qf[idx][kst], sa, 0, 0, 0);
      const int s = st[idx] * 16 + l15;
      const float Ms = Msd[s];
      float vr[4];
      #pragma unroll
      for (int rr = 0; rr < 4; ++rr) {
        const int r = rt * 16 + g16 * 4 + rr;
        float w = (r <= s) ? __expf(Gqe[rr] - Ms) * SCALE : 0.f;
        vr[rr] = sa[rr] * w;
      }
      qns[idx] += vr[0] + vr[1] + vr[2] + vr[3];
      *(uint2*)swp(Plds, s, (rt * 16 + g16 * 4) * 2) =
          make_uint2(pk2h(vr[0], vr[1]), pk2h(vr[2], vr[3]));
    }
  }
  #pragma unroll
  for (int idx = 0; idx < 2; ++idx) {
    float p = qns[idx];
    p += __shfl_xor(p, 16); p += __shfl_xor(p, 32);
    if (g16 == 0) {
      const int s = st[idx] * 16 + l15;
      qnS[s] = p + alph[s] * qn2[idx];
    }
  }
  __syncthreads();

  // ---- PV: acc += P @ V ----
  const int kmax0 = ((st[0] | 1) + 1) >> 1;
  const int kmax1 = ((st[1] | 1) + 1) >> 1;
  #pragma unroll
  for (int kst = 0; kst < 4; ++kst) {
    if (kst < kmax1) {
      f16x8 vf[8];
      #pragma unroll
      for (int jt = 0; jt < 8; ++jt)
        vf[jt] = *(f16x8*)swp(stage, jt * 16 + l15, (kst * 32 + g16 * 8) * 2);
      if (kst < kmax0) {
        f16x8 pf = *(f16x8*)swp(Plds, st[0] * 16 + l15, (kst * 32 + g16 * 8) * 2);
        #pragma unroll
        for (int jt = 0; jt < 8; ++jt)
          acc[0][jt] = __builtin_amdgcn_mfma_f32_16x16x32_f16(pf, vf[jt], acc[0][jt], 0, 0, 0);
      }
      {
        f16x8 pf = *(f16x8*)swp(Plds, st[1] * 16 + l15, (kst * 32 + g16 * 8) * 2);
        #pragma unroll
        for (int jt = 0; jt < 8; ++jt)
          acc[1][jt] = __builtin_amdgcn_mfma_f32_16x16x32_f16(pf, vf[jt], acc[1][jt], 0, 0, 0);
      }
    }
  }

  // ---- epilogue: denom, LayerNorm, store ----
  const float* lw = lnw + hh * DHD;
  float lwv[8];
  #pragma unroll
  for (int jt = 0; jt < 8; ++jt) lwv[jt] = lw[jt * 16 + l15];

  #pragma unroll
  for (int idx = 0; idx < 2; ++idx) {
    const int s0 = st[idx] * 16 + g16 * 4;
    float4 qnq = *(const float4*)&qnS[s0];
    float4 Bq  = *(const float4*)&Bsd[s0];
    float4 Mq  = *(const float4*)&Msd[s0];
    const float* qne = (const float*)&qnq;
    const float* Be  = (const float*)&Bq;
    const float* Me  = (const float*)&Mq;
    #pragma unroll
    for (int reg = 0; reg < 4; ++reg) {
      float den = fmaxf(fabsf(qne[reg]), __expf(-(Be[reg] + Me[reg]))) + 1e-6f;
      float inv = 1.0f / den;
      float mp = 0.f, sp = 0.f;
      float hv[8];
      #pragma unroll
      for (int jt = 0; jt < 8; ++jt) {
        float h = acc[idx][jt][reg] * inv;
        hv[jt] = h;
        mp += h; sp += h * h;
      }
      mp += __shfl_xor(mp, 1); sp += __shfl_xor(sp, 1);
      mp += __shfl_xor(mp, 2); sp += __shfl_xor(sp, 2);
      mp += __shfl_xor(mp, 4); sp += __shfl_xor(sp, 4);
      mp += __shfl_xor(mp, 8); sp += __shfl_xor(sp, 8);
      float mu = mp * (1.f / 128.f);
      float var = fmaxf(sp * (1.f / 128.f) - mu * mu, 0.f);
      float rstd = rsqrtf(var + 1e-6f);
      float* orow = out + (size_t)(b * SS + t0 + s0 + reg) * DD + hh * DHD;
      #pragma unroll
      for (int jt = 0; jt < 8; ++jt)
        orow[jt * 16 + l15] = (hv[jt] - mu) * rstd * lwv[jt];
    }
  }
}

extern "C" void kernel_launch(void* const* d_in, const int* in_sizes, int n_in,
                              void* d_out, int out_size, void* d_ws, size_t ws_size,
                              hipStream_t stream) {
  const float* q   = (const float*)d_in[0];
  const float* k   = (const float*)d_in[1];
  const float* v   = (const float*)d_in[2];
  const float* c0  = (const float*)d_in[3];
  const float* n0  = (const float*)d_in[4];
  const float* m0  = (const float*)d_in[5];
  const float* Wi  = (const float*)d_in[6];
  const float* bi  = (const float*)d_in[7];
  const float* Wf  = (const float*)d_in[8];
  const float* bf  = (const float*)d_in[9];
  const float* lnw = (const float*)d_in[10];
  float* out = (float*)d_out;
  float* ws  = (float*)d_ws;

  gates_kernel<<<BB * SS / 4, 64, 0, stream>>>(q, k, v, Wi, bi, Wf, bf,
                                               ws + OFF_IG, ws + OFF_LF);
  prep_kernel<<<BB * NHD, 128, 0, stream>>>(ws, m0, out);
  u_kernel<<<BB * NHD * NC, 256, 65536, stream>>>(k, v, ws);
  cprefix_kernel<<<BB * NHD * 64, 256, 0, stream>>>(c0, ws, out);
  nprefix_kernel<<<BB * NHD, 128, 0, stream>>>(n0, ws, out);
  intra_kernel<<<BB * NHD * NC, 256, 69632, stream>>>(q, k, v, lnw, ws, out);
}

// Round 6
// 147.303 us; speedup vs baseline: 7.0373x; 1.1180x over previous
//
#include <hip/hip_runtime.h>
#include <math.h>

#define BB 4
#define SS 2048
#define DD 1024
#define NHD 8
#define DHD 128
#define NC 16
#define CL 128
#define SCALE 0.08838834764831845f

// workspace offsets (in floats)
#define OFF_IG   0
#define OFF_LF   65536
#define OFF_B    131072
#define OFF_G    196608
#define OFF_E    262144
#define OFF_RM   327680
#define OFF_MIN  393216
#define OFF_SC   393728
#define OFF_UN   396288
#define OFF_NIN  461824
#define OFF_U    527360
// out offsets (floats)
#define OUT_C  8388608
#define OUT_N  8912896
#define OUT_M  8916992

typedef __attribute__((ext_vector_type(8))) _Float16 f16x8;
typedef __attribute__((ext_vector_type(4))) float f32x4;

__device__ __forceinline__ unsigned pk2h(float a, float b) {
  union { _Float16 h[2]; unsigned u; } f;
  f.h[0] = (_Float16)a; f.h[1] = (_Float16)b;
  return f.u;
}
__device__ __forceinline__ f16x8 mkfrag(float4 a, float4 c) {
  f16x8 f;
  f[0] = (_Float16)a.x; f[1] = (_Float16)a.y; f[2] = (_Float16)a.z; f[3] = (_Float16)a.w;
  f[4] = (_Float16)c.x; f[5] = (_Float16)c.y; f[6] = (_Float16)c.z; f[7] = (_Float16)c.w;
  return f;
}
// 256B rows, XOR-swizzle byte bits 4..6 with row&7 (m214 attn recipe)
__device__ __forceinline__ char* swp(char* base, int row, int byte) {
  return base + (((row << 8) + byte) ^ ((row & 7) << 4));
}

// ---------------------------------------------------------------------------
// Kernel 0 (NEW): transpose Wi|Wf (3072x8 each, f32) -> WT f16 [16][3072].
// WT lives in the OFF_U region (dead until u_kernel runs later in-stream).
// ---------------------------------------------------------------------------
__global__ __launch_bounds__(256) void wtrans_kernel(const float* __restrict__ Wi,
                                                     const float* __restrict__ Wf,
                                                     _Float16* __restrict__ WT) {
  const int kk = blockIdx.x * 256 + threadIdx.x;   // 0..3071
  float4 wa = *(const float4*)(Wi + (size_t)kk * 8);
  float4 wb = *(const float4*)(Wi + (size_t)kk * 8 + 4);
  float4 fa = *(const float4*)(Wf + (size_t)kk * 8);
  float4 fb = *(const float4*)(Wf + (size_t)kk * 8 + 4);
  WT[0 * 3072 + kk]  = (_Float16)wa.x; WT[1 * 3072 + kk]  = (_Float16)wa.y;
  WT[2 * 3072 + kk]  = (_Float16)wa.z; WT[3 * 3072 + kk]  = (_Float16)wa.w;
  WT[4 * 3072 + kk]  = (_Float16)wb.x; WT[5 * 3072 + kk]  = (_Float16)wb.y;
  WT[6 * 3072 + kk]  = (_Float16)wb.z; WT[7 * 3072 + kk]  = (_Float16)wb.w;
  WT[8 * 3072 + kk]  = (_Float16)fa.x; WT[9 * 3072 + kk]  = (_Float16)fa.y;
  WT[10 * 3072 + kk] = (_Float16)fa.z; WT[11 * 3072 + kk] = (_Float16)fa.w;
  WT[12 * 3072 + kk] = (_Float16)fb.x; WT[13 * 3072 + kk] = (_Float16)fb.y;
  WT[14 * 3072 + kk] = (_Float16)fb.z; WT[15 * 3072 + kk] = (_Float16)fb.w;
}

// ---------------------------------------------------------------------------
// Kernel 1 (NEW): gates via MFMA.  [8192x3072]@[3072x16] K-split over 4 waves.
// Block = 256 thr, 16 time-rows; wave w owns K-steps [w*24, w*24+24).
// A-frag: 8 consecutive fp32 from q/k/v row (validated layout); B-frag: 16B
// contiguous f16 from WT.  LDS reduce over the 4 K-partials, fused epilogue.
// ---------------------------------------------------------------------------
__global__ __launch_bounds__(256) void gates_kernel(
    const float* __restrict__ q, const float* __restrict__ k, const float* __restrict__ v,
    const _Float16* __restrict__ WT, const float* __restrict__ bi,
    const float* __restrict__ bfb,
    float* __restrict__ ig_ws, float* __restrict__ lf_ws) {
  __shared__ float red[4][256];
  const int tid = threadIdx.x, wid = tid >> 6, lane = tid & 63;
  const int g16 = lane >> 4, l15 = lane & 15;
  const int g0 = blockIdx.x * 16;
  const int b = g0 >> 11, t0 = g0 & (SS - 1);

  const size_t rowoff = (size_t)b * SS * DD + (size_t)(t0 + l15) * DD;
  const float* bases[3] = {q + rowoff, k + rowoff, v + rowoff};

  f32x4 acc = {0.f, 0.f, 0.f, 0.f};
  const int ks0 = wid * 24;
  #pragma unroll 1
  for (int grp = 0; grp < 3; ++grp) {
    const int s0 = ks0 + grp * 8;                   // group of 8 K-steps, segment-uniform
    const float* Ab = bases[s0 >> 5] + (s0 & 31) * 32 + g16 * 8;
    const _Float16* Bb = WT + l15 * 3072 + s0 * 32 + g16 * 8;
    float4 a[8], c[8]; f16x8 bfr[8];
    #pragma unroll
    for (int j = 0; j < 8; ++j) {
      a[j]   = *(const float4*)(Ab + j * 32);
      c[j]   = *(const float4*)(Ab + j * 32 + 4);
      bfr[j] = *(const f16x8*)(Bb + j * 32);
    }
    #pragma unroll
    for (int j = 0; j < 8; ++j)
      acc = __builtin_amdgcn_mfma_f32_16x16x32_f16(mkfrag(a[j], c[j]), bfr[j], acc, 0, 0, 0);
  }
  #pragma unroll
  for (int r = 0; r < 4; ++r) red[wid][(g16 * 4 + r) * 16 + l15] = acc[r];
  __syncthreads();

  float s = red[0][tid] + red[1][tid] + red[2][tid] + red[3][tid];
  const int row = tid >> 4, gate = tid & 15;
  const int t = t0 + row;
  if (gate < 8) {
    ig_ws[(size_t)(b * NHD + gate) * SS + t] = s + bi[gate];
  } else {
    float ft = s + bfb[gate - 8];
    float lf = fminf(ft, 0.f) - log1pf(expf(-fabsf(ft)));
    lf_ws[(size_t)(b * NHD + gate - 8) * SS + t] = lf;
  }
}

// ---------------------------------------------------------------------------
// Kernel 2: prep (validated).
// ---------------------------------------------------------------------------
__global__ __launch_bounds__(128) void prep_kernel(float* __restrict__ ws,
                                                   const float* __restrict__ m0,
                                                   float* __restrict__ out) {
  const int bh = blockIdx.x;
  const int s  = threadIdx.x;
  __shared__ float sh[128];
  __shared__ float bc2[2];
  __shared__ float mina[NC], mxga[NC], lfsa[NC];
  const float* lf = ws + OFF_LF + (size_t)bh * SS;
  const float* ig = ws + OFF_IG + (size_t)bh * SS;
  const float m0v = m0[bh];
  float m_run = m0v, LFtot = 0.f;
  for (int g = 0; g < NC; ++g) {
    const int t = g * CL + s;
    float lfv = lf[t], iv = ig[t];
    float v = lfv;
    sh[s] = v; __syncthreads();
    for (int off = 1; off < 128; off <<= 1) {
      float tv = (s >= off) ? sh[s - off] : 0.f;
      __syncthreads();
      v += tv; sh[s] = v; __syncthreads();
    }
    float Bv = v;
    float Gv = iv - Bv;
    v = Gv; sh[s] = v; __syncthreads();
    for (int off = 1; off < 128; off <<= 1) {
      float tv = (s >= off) ? sh[s - off] : -3.0e38f;
      __syncthreads();
      v = fmaxf(v, tv); sh[s] = v; __syncthreads();
    }
    float Rv = v;
    if (s == 127) { bc2[0] = Bv; bc2[1] = Rv; }
    __syncthreads();
    float Bend = bc2[0], mxG = bc2[1];
    __syncthreads();
    ws[OFF_B  + (size_t)bh * SS + t] = Bv;
    ws[OFF_G  + (size_t)bh * SS + t] = Gv;
    ws[OFF_RM + (size_t)bh * SS + t] = fmaxf(m_run, Rv);
    ws[OFF_E  + (size_t)bh * SS + t] = expf(Gv - mxG);
    if (s == 0) {
      ws[OFF_MIN + bh * NC + g] = m_run;
      mina[g] = m_run; mxga[g] = mxG; lfsa[g] = LFtot;
    }
    m_run = Bend + fmaxf(m_run, mxG);
    LFtot += Bend;
  }
  if (s == 0) {
    out[OUT_M + bh] = m_run;
    float* sc = ws + OFF_SC + bh * 80;
    float S = -3.0e38f;
    for (int g = 0; g < NC; ++g) {
      float r_g = lfsa[g] - mina[g];
      sc[g]      = expf(S + r_g);
      sc[20 + g] = expf(m0v + lfsa[g] - mina[g]);
      float s_g = mxga[g] - lfsa[g];
      float Sn = fmaxf(S, s_g);
      sc[40 + g] = expf(S - Sn);
      sc[60 + g] = expf(s_g - Sn);
      S = Sn;
    }
    float r16 = LFtot - m_run;
    sc[16] = expf(S + r16);
    sc[36] = expf(m0v + LFtot - m_run);
  }
}

// ---------------------------------------------------------------------------
// Kernel 3: MFMA U^(g) = K̂ᵀ·diag(E)·V + fused Un row-sums (validated r5).
// ---------------------------------------------------------------------------
__global__ __launch_bounds__(256, 2) void u_kernel(const float* __restrict__ k,
                                                   const float* __restrict__ v,
                                                   float* __restrict__ ws) {
  extern __shared__ char smem[];
  char* Kt = smem;
  char* Vt = smem + 32768;

  const int tid = threadIdx.x;
  const int wid = tid >> 6;
  const int lane = tid & 63;
  const int g16 = lane >> 4;
  const int l15 = lane & 15;
  const int g  = blockIdx.x & 15;
  const int bh = blockIdx.x >> 4;
  const int b = bh >> 3, hh = bh & 7;
  const size_t headoff = (size_t)b * SS * DD + (size_t)hh * SS * DHD;
  const float* kb = k + headoff + (size_t)g * CL * DHD;
  const float* vb = v + headoff + (size_t)g * CL * DHD;
  const float* E  = ws + OFF_E + (size_t)bh * SS + g * CL;

  #pragma unroll 4
  for (int it = 0; it < 16; ++it) {
    const int idx = (it << 8) + tid;
    const int c  = idx & 127;
    const int r0 = (idx >> 7) << 2;
    float e0 = E[r0] * SCALE, e1 = E[r0 + 1] * SCALE,
          e2 = E[r0 + 2] * SCALE, e3 = E[r0 + 3] * SCALE;
    float a0 = kb[(size_t)r0 * DHD + c] * e0;
    float a1 = kb[(size_t)(r0 + 1) * DHD + c] * e1;
    float a2 = kb[(size_t)(r0 + 2) * DHD + c] * e2;
    float a3 = kb[(size_t)(r0 + 3) * DHD + c] * e3;
    *(uint2*)swp(Kt, c, r0 * 2) = make_uint2(pk2h(a0, a1), pk2h(a2, a3));
    float b0 = vb[(size_t)r0 * DHD + c];
    float b1 = vb[(size_t)(r0 + 1) * DHD + c];
    float b2 = vb[(size_t)(r0 + 2) * DHD + c];
    float b3 = vb[(size_t)(r0 + 3) * DHD + c];
    *(uint2*)swp(Vt, c, r0 * 2) = make_uint2(pk2h(b0, b1), pk2h(b2, b3));
  }
  __syncthreads();

  if (tid < 128) {
    float s = 0.f;
    #pragma unroll
    for (int r8 = 0; r8 < 16; ++r8) {
      f16x8 x = *(f16x8*)swp(Kt, tid, r8 * 16);
      s += (float)x[0] + (float)x[1] + (float)x[2] + (float)x[3]
         + (float)x[4] + (float)x[5] + (float)x[6] + (float)x[7];
    }
    ws[OFF_UN + (size_t)(bh * NC + g) * DHD + tid] = s;
  }

  float* Ubuf = ws + OFF_U + (size_t)(bh * NC + g) * (DHD * DHD);
  const int it0 = wid * 2;
  #pragma unroll 1
  for (int jt = 0; jt < 8; ++jt) {
    f32x4 a0 = {0.f, 0.f, 0.f, 0.f}, a1 = {0.f, 0.f, 0.f, 0.f};
    #pragma unroll
    for (int kst = 0; kst < 4; ++kst) {
      const int byte = (kst * 32 + g16 * 8) * 2;
      f16x8 bf0 = *(f16x8*)swp(Vt, jt * 16 + l15, byte);
      f16x8 af0 = *(f16x8*)swp(Kt, it0 * 16 + l15, byte);
      f16x8 af1 = *(f16x8*)swp(Kt, (it0 + 1) * 16 + l15, byte);
      a0 = __builtin_amdgcn_mfma_f32_16x16x32_f16(af0, bf0, a0, 0, 0, 0);
      a1 = __builtin_amdgcn_mfma_f32_16x16x32_f16(af1, bf0, a1, 0, 0, 0);
    }
    #pragma unroll
    for (int reg = 0; reg < 4; ++reg) {
      Ubuf[(size_t)(it0 * 16 + g16 * 4 + reg) * DHD + jt * 16 + l15] = a0[reg];
      Ubuf[(size_t)((it0 + 1) * 16 + g16 * 4 + reg) * DHD + jt * 16 + l15] = a1[reg];
    }
  }
}

// ---------------------------------------------------------------------------
// Kernel 4: prefix combine (validated).
// ---------------------------------------------------------------------------
__global__ __launch_bounds__(256) void cprefix_kernel(const float* __restrict__ c0,
                                                      float* __restrict__ ws,
                                                      float* __restrict__ out) {
  const int bh = blockIdx.x >> 6;
  const int elem = ((blockIdx.x & 63) << 8) + threadIdx.x;
  const float* sc = ws + OFF_SC + bh * 80;
  float c0v = c0[(size_t)bh * 16384 + elem];
  float* Ub = ws + OFF_U + (size_t)bh * NC * 16384 + elem;
  float P = 0.f;
  #pragma unroll 1
  for (int g = 0; g < NC; ++g) {
    float u = Ub[(size_t)g * 16384];
    Ub[(size_t)g * 16384] = sc[g] * P + sc[20 + g] * c0v;
    P = sc[40 + g] * P + sc[60 + g] * u;
  }
  out[OUT_C + (size_t)bh * 16384 + elem] = sc[16] * P + sc[36] * c0v;
}

__global__ __launch_bounds__(128) void nprefix_kernel(const float* __restrict__ n0,
                                                      float* __restrict__ ws,
                                                      float* __restrict__ out) {
  const int bh = blockIdx.x;
  const int i = threadIdx.x;
  const float* sc = ws + OFF_SC + bh * 80;
  float n0v = n0[bh * DHD + i];
  const float* Ub = ws + OFF_UN + (size_t)bh * NC * DHD + i;
  float* Nb = ws + OFF_NIN + (size_t)bh * NC * DHD + i;
  float P = 0.f;
  #pragma unroll 1
  for (int g = 0; g < NC; ++g) {
    float u = Ub[g * DHD];
    Nb[g * DHD] = sc[g] * P + sc[20 + g] * n0v;
    P = sc[40 + g] * P + sc[60 + g] * u;
  }
  out[OUT_N + bh * DHD + i] = sc[16] * P + sc[36] * n0v;
}

// ---------------------------------------------------------------------------
// Kernel 5: MFMA intra-chunk attention + inter + denom + fused LN (validated).
// ---------------------------------------------------------------------------
__global__ __launch_bounds__(256, 2) void intra_kernel(
    const float* __restrict__ q, const float* __restrict__ k, const float* __restrict__ v,
    const float* __restrict__ lnw, float* __restrict__ ws, float* __restrict__ out) {
  extern __shared__ char smem[];
  char* Plds  = smem;
  char* stage = smem + 32768;
  float* Gs   = (float*)(smem + 65536);
  float* Msd  = Gs + 128;
  float* Bsd  = Gs + 256;
  float* alph = Gs + 384;
  float* ninS = Gs + 512;
  float* qnS  = Gs + 640;

  const int tid = threadIdx.x;
  const int wid = tid >> 6;
  const int lane = tid & 63;
  const int g16 = lane >> 4;
  const int l15 = lane & 15;
  const int g = blockIdx.x & 15;
  const int bh = blockIdx.x >> 4;
  const int b = bh >> 3, hh = bh & 7;
  const int t0 = g * CL;

  const size_t headoff = (size_t)b * SS * DD + (size_t)hh * SS * DHD;
  const float* qb = q + headoff;
  const float* kb = k + headoff;
  const float* vb = v + headoff;
  const float m_in = ws[OFF_MIN + bh * NC + g];

  if (tid < 128) {
    float M = ws[OFF_RM + (size_t)bh * SS + t0 + tid];
    Msd[tid] = M;
    alph[tid] = __expf(m_in - M);
    Gs[tid]  = ws[OFF_G + (size_t)bh * SS + t0 + tid];
    Bsd[tid] = ws[OFF_B + (size_t)bh * SS + t0 + tid];
    ninS[tid] = ws[OFF_NIN + (size_t)(bh * NC + g) * DHD + tid];
  }
  __syncthreads();

  const int st[2] = {wid, wid + 4};

  auto stageT = [&](const float* src) {
    #pragma unroll 4
    for (int it = 0; it < 16; ++it) {
      const int idx = (it << 8) + tid;
      const int j = idx & 127;
      const int r0 = (idx >> 7) << 2;
      float a0 = src[(size_t)r0 * DHD + j];
      float a1 = src[(size_t)(r0 + 1) * DHD + j];
      float a2 = src[(size_t)(r0 + 2) * DHD + j];
      float a3 = src[(size_t)(r0 + 3) * DHD + j];
      *(uint2*)swp(stage, j, r0 * 2) = make_uint2(pk2h(a0, a1), pk2h(a2, a3));
    }
  };

  // ---- phase A: Q fragments + qn2 ----
  f16x8 qf[2][4];
  float qn2[2];
  #pragma unroll
  for (int idx = 0; idx < 2; ++idx) {
    const float* qrow = qb + (size_t)(t0 + st[idx] * 16 + l15) * DHD + g16 * 8;
    float p = 0.f;
    #pragma unroll
    for (int kst = 0; kst < 4; ++kst) {
      float4 a = *(const float4*)(qrow + kst * 32);
      float4 c = *(const float4*)(qrow + kst * 32 + 4);
      qf[idx][kst] = mkfrag(a, c);
      const float* nn = &ninS[kst * 32 + g16 * 8];
      p += a.x * nn[0] + a.y * nn[1] + a.z * nn[2] + a.w * nn[3]
         + c.x * nn[4] + c.y * nn[5] + c.z * nn[6] + c.w * nn[7];
    }
    p += __shfl_xor(p, 16); p += __shfl_xor(p, 32);
    qn2[idx] = p;
  }

  // ---- stage Cin^T (f16) ----
  stageT(ws + OFF_U + (size_t)(bh * NC + g) * (DHD * DHD));
  __syncthreads();

  // ---- QC: acc = Q @ Cin ----
  f32x4 acc[2][8];
  #pragma unroll
  for (int jt = 0; jt < 8; ++jt) {
    f32x4 a0 = {0.f, 0.f, 0.f, 0.f}, a1 = {0.f, 0.f, 0.f, 0.f};
    #pragma unroll
    for (int kst = 0; kst < 4; ++kst) {
      f16x8 bfr = *(f16x8*)swp(stage, jt * 16 + l15, (kst * 32 + g16 * 8) * 2);
      a0 = __builtin_amdgcn_mfma_f32_16x16x32_f16(qf[0][kst], bfr, a0, 0, 0, 0);
      a1 = __builtin_amdgcn_mfma_f32_16x16x32_f16(qf[1][kst], bfr, a1, 0, 0, 0);
    }
    acc[0][jt] = a0; acc[1][jt] = a1;
  }
  #pragma unroll
  for (int idx = 0; idx < 2; ++idx) {
    float4 av = *(const float4*)&alph[st[idx] * 16 + g16 * 4];
    #pragma unroll
    for (int jt = 0; jt < 8; ++jt) {
      acc[idx][jt][0] *= av.x; acc[idx][jt][1] *= av.y;
      acc[idx][jt][2] *= av.z; acc[idx][jt][3] *= av.w;
    }
  }
  __syncthreads();

  // ---- stage V^T (f16) ----
  stageT(vb + (size_t)t0 * DHD);

  // ---- S-phase ----
  float qns[2] = {0.f, 0.f};
  const int rtmax = st[1] | 1;
  #pragma unroll 1
  for (int rt = 0; rt <= rtmax; ++rt) {
    f16x8 kf[4];
    const float* krow = kb + (size_t)(t0 + rt * 16 + l15) * DHD + g16 * 8;
    #pragma unroll
    for (int kst = 0; kst < 4; ++kst)
      kf[kst] = mkfrag(*(const float4*)(krow + kst * 32),
                       *(const float4*)(krow + kst * 32 + 4));
    float4 Gq = *(const float4*)&Gs[rt * 16 + g16 * 4];
    const float* Gqe = (const float*)&Gq;
    #pragma unroll
    for (int idx = 0; idx < 2; ++idx) {
      if (rt > (st[idx] | 1)) continue;
      f32x4 sa = {0.f, 0.f, 0.f, 0.f};
      #pragma unroll
      for (int kst = 0; kst < 4; ++kst)
        sa = __builtin_amdgcn_mfma_f32_16x16x32_f16(kf[kst], qf[idx][kst], sa, 0, 0, 0);
      const int s = st[idx] * 16 + l15;
      const float Ms = Msd[s];
      float vr[4];
      #pragma unroll
      for (int rr = 0; rr < 4; ++rr) {
        const int r = rt * 16 + g16 * 4 + rr;
        float w = (r <= s) ? __expf(Gqe[rr] - Ms) * SCALE : 0.f;
        vr[rr] = sa[rr] * w;
      }
      qns[idx] += vr[0] + vr[1] + vr[2] + vr[3];
      *(uint2*)swp(Plds, s, (rt * 16 + g16 * 4) * 2) =
          make_uint2(pk2h(vr[0], vr[1]), pk2h(vr[2], vr[3]));
    }
  }
  #pragma unroll
  for (int idx = 0; idx < 2; ++idx) {
    float p = qns[idx];
    p += __shfl_xor(p, 16); p += __shfl_xor(p, 32);
    if (g16 == 0) {
      const int s = st[idx] * 16 + l15;
      qnS[s] = p + alph[s] * qn2[idx];
    }
  }
  __syncthreads();

  // ---- PV ----
  const int kmax0 = ((st[0] | 1) + 1) >> 1;
  const int kmax1 = ((st[1] | 1) + 1) >> 1;
  #pragma unroll
  for (int kst = 0; kst < 4; ++kst) {
    if (kst < kmax1) {
      f16x8 vf[8];
      #pragma unroll
      for (int jt = 0; jt < 8; ++jt)
        vf[jt] = *(f16x8*)swp(stage, jt * 16 + l15, (kst * 32 + g16 * 8) * 2);
      if (kst < kmax0) {
        f16x8 pf = *(f16x8*)swp(Plds, st[0] * 16 + l15, (kst * 32 + g16 * 8) * 2);
        #pragma unroll
        for (int jt = 0; jt < 8; ++jt)
          acc[0][jt] = __builtin_amdgcn_mfma_f32_16x16x32_f16(pf, vf[jt], acc[0][jt], 0, 0, 0);
      }
      {
        f16x8 pf = *(f16x8*)swp(Plds, st[1] * 16 + l15, (kst * 32 + g16 * 8) * 2);
        #pragma unroll
        for (int jt = 0; jt < 8; ++jt)
          acc[1][jt] = __builtin_amdgcn_mfma_f32_16x16x32_f16(pf, vf[jt], acc[1][jt], 0, 0, 0);
      }
    }
  }

  // ---- epilogue ----
  const float* lw = lnw + hh * DHD;
  float lwv[8];
  #pragma unroll
  for (int jt = 0; jt < 8; ++jt) lwv[jt] = lw[jt * 16 + l15];

  #pragma unroll
  for (int idx = 0; idx < 2; ++idx) {
    const int s0 = st[idx] * 16 + g16 * 4;
    float4 qnq = *(const float4*)&qnS[s0];
    float4 Bq  = *(const float4*)&Bsd[s0];
    float4 Mq  = *(const float4*)&Msd[s0];
    const float* qne = (const float*)&qnq;
    const float* Be  = (const float*)&Bq;
    const float* Me  = (const float*)&Mq;
    #pragma unroll
    for (int reg = 0; reg < 4; ++reg) {
      float den = fmaxf(fabsf(qne[reg]), __expf(-(Be[reg] + Me[reg]))) + 1e-6f;
      float inv = 1.0f / den;
      float mp = 0.f, sp = 0.f;
      float hv[8];
      #pragma unroll
      for (int jt = 0; jt < 8; ++jt) {
        float h = acc[idx][jt][reg] * inv;
        hv[jt] = h;
        mp += h; sp += h * h;
      }
      mp += __shfl_xor(mp, 1); sp += __shfl_xor(sp, 1);
      mp += __shfl_xor(mp, 2); sp += __shfl_xor(sp, 2);
      mp += __shfl_xor(mp, 4); sp += __shfl_xor(sp, 4);
      mp += __shfl_xor(mp, 8); sp += __shfl_xor(sp, 8);
      float mu = mp * (1.f / 128.f);
      float var = fmaxf(sp * (1.f / 128.f) - mu * mu, 0.f);
      float rstd = rsqrtf(var + 1e-6f);
      float* orow = out + (size_t)(b * SS + t0 + s0 + reg) * DD + hh * DHD;
      #pragma unroll
      for (int jt = 0; jt < 8; ++jt)
        orow[jt * 16 + l15] = (hv[jt] - mu) * rstd * lwv[jt];
    }
  }
}

extern "C" void kernel_launch(void* const* d_in, const int* in_sizes, int n_in,
                              void* d_out, int out_size, void* d_ws, size_t ws_size,
                              hipStream_t stream) {
  const float* q   = (const float*)d_in[0];
  const float* k   = (const float*)d_in[1];
  const float* v   = (const float*)d_in[2];
  const float* c0  = (const float*)d_in[3];
  const float* n0  = (const float*)d_in[4];
  const float* m0  = (const float*)d_in[5];
  const float* Wi  = (const float*)d_in[6];
  const float* bi  = (const float*)d_in[7];
  const float* Wf  = (const float*)d_in[8];
  const float* bf  = (const float*)d_in[9];
  const float* lnw = (const float*)d_in[10];
  float* out = (float*)d_out;
  float* ws  = (float*)d_ws;

  _Float16* WT = (_Float16*)(ws + OFF_U);   // dead region until u_kernel writes it

  wtrans_kernel<<<12, 256, 0, stream>>>(Wi, Wf, WT);
  gates_kernel<<<BB * SS / 16, 256, 0, stream>>>(q, k, v, WT, bi, bf,
                                                 ws + OFF_IG, ws + OFF_LF);
  prep_kernel<<<BB * NHD, 128, 0, stream>>>(ws, m0, out);
  u_kernel<<<BB * NHD * NC, 256, 65536, stream>>>(k, v, ws);
  cprefix_kernel<<<BB * NHD * 64, 256, 0, stream>>>(c0, ws, out);
  nprefix_kernel<<<BB * NHD, 128, 0, stream>>>(n0, ws, out);
  intra_kernel<<<BB * NHD * NC, 256, 69632, stream>>>(q, k, v, lnw, ws, out);
}

// Round 7
// 143.312 us; speedup vs baseline: 7.2333x; 1.0278x over previous
//
#include <hip/hip_runtime.h>
#include <math.h>

#define BB 4
#define SS 2048
#define DD 1024
#define NHD 8
#define DHD 128
#define NC 16
#define CL 128
#define SCALE 0.08838834764831845f

// workspace offsets (in floats)
#define OFF_IG   0
#define OFF_LF   65536
#define OFF_B    131072
#define OFF_G    196608
#define OFF_E    262144
#define OFF_RM   327680
#define OFF_MIN  393216
#define OFF_SC   393728
#define OFF_UN   396288
#define OFF_NIN  461824
#define OFF_U    527360
// out offsets (floats)
#define OUT_C  8388608
#define OUT_N  8912896
#define OUT_M  8916992

typedef __attribute__((ext_vector_type(8))) _Float16 f16x8;
typedef __attribute__((ext_vector_type(4))) float f32x4;

__device__ __forceinline__ unsigned pk2h(float a, float b) {
  union { _Float16 h[2]; unsigned u; } f;
  f.h[0] = (_Float16)a; f.h[1] = (_Float16)b;
  return f.u;
}
__device__ __forceinline__ f16x8 mkfrag(float4 a, float4 c) {
  f16x8 f;
  f[0] = (_Float16)a.x; f[1] = (_Float16)a.y; f[2] = (_Float16)a.z; f[3] = (_Float16)a.w;
  f[4] = (_Float16)c.x; f[5] = (_Float16)c.y; f[6] = (_Float16)c.z; f[7] = (_Float16)c.w;
  return f;
}
// 256B rows, XOR-swizzle byte bits 4..6 with row&7 (m214 attn recipe)
__device__ __forceinline__ char* swp(char* base, int row, int byte) {
  return base + (((row << 8) + byte) ^ ((row & 7) << 4));
}

// ---------------------------------------------------------------------------
// Kernel 0: transpose Wi|Wf (3072x8 each, f32) -> WT f16 [16][3072] (validated).
// ---------------------------------------------------------------------------
__global__ __launch_bounds__(256) void wtrans_kernel(const float* __restrict__ Wi,
                                                     const float* __restrict__ Wf,
                                                     _Float16* __restrict__ WT) {
  const int kk = blockIdx.x * 256 + threadIdx.x;   // 0..3071
  float4 wa = *(const float4*)(Wi + (size_t)kk * 8);
  float4 wb = *(const float4*)(Wi + (size_t)kk * 8 + 4);
  float4 fa = *(const float4*)(Wf + (size_t)kk * 8);
  float4 fb = *(const float4*)(Wf + (size_t)kk * 8 + 4);
  WT[0 * 3072 + kk]  = (_Float16)wa.x; WT[1 * 3072 + kk]  = (_Float16)wa.y;
  WT[2 * 3072 + kk]  = (_Float16)wa.z; WT[3 * 3072 + kk]  = (_Float16)wa.w;
  WT[4 * 3072 + kk]  = (_Float16)wb.x; WT[5 * 3072 + kk]  = (_Float16)wb.y;
  WT[6 * 3072 + kk]  = (_Float16)wb.z; WT[7 * 3072 + kk]  = (_Float16)wb.w;
  WT[8 * 3072 + kk]  = (_Float16)fa.x; WT[9 * 3072 + kk]  = (_Float16)fa.y;
  WT[10 * 3072 + kk] = (_Float16)fa.z; WT[11 * 3072 + kk] = (_Float16)fa.w;
  WT[12 * 3072 + kk] = (_Float16)fb.x; WT[13 * 3072 + kk] = (_Float16)fb.y;
  WT[14 * 3072 + kk] = (_Float16)fb.z; WT[15 * 3072 + kk] = (_Float16)fb.w;
}

// ---------------------------------------------------------------------------
// Kernel 1: gates via MFMA, 512 thr / 8-wave K-split (12 K-steps per wave,
// groups of 4 — group never crosses a q/k/v segment boundary).
// ---------------------------------------------------------------------------
__global__ __launch_bounds__(512) void gates_kernel(
    const float* __restrict__ q, const float* __restrict__ k, const float* __restrict__ v,
    const _Float16* __restrict__ WT, const float* __restrict__ bi,
    const float* __restrict__ bfb,
    float* __restrict__ ig_ws, float* __restrict__ lf_ws) {
  __shared__ float red[8][256];
  const int tid = threadIdx.x, wid = tid >> 6, lane = tid & 63;
  const int g16 = lane >> 4, l15 = lane & 15;
  const int g0 = blockIdx.x * 16;
  const int b = g0 >> 11, t0 = g0 & (SS - 1);

  const size_t rowoff = (size_t)b * SS * DD + (size_t)(t0 + l15) * DD;
  const float* qr = q + rowoff;
  const float* kr = k + rowoff;
  const float* vr = v + rowoff;

  f32x4 acc = {0.f, 0.f, 0.f, 0.f};
  const int ks0 = wid * 12;
  #pragma unroll
  for (int grp = 0; grp < 3; ++grp) {
    const int s0 = ks0 + grp * 4;                  // 4 K-steps, segment-uniform
    const int seg = s0 >> 5;
    const float* base = (seg == 0) ? qr : (seg == 1) ? kr : vr;
    const float* Ab = base + (s0 & 31) * 32 + g16 * 8;
    const _Float16* Bb = WT + l15 * 3072 + s0 * 32 + g16 * 8;
    float4 a[4], c[4]; f16x8 bfr[4];
    #pragma unroll
    for (int j = 0; j < 4; ++j) {
      a[j]   = *(const float4*)(Ab + j * 32);
      c[j]   = *(const float4*)(Ab + j * 32 + 4);
      bfr[j] = *(const f16x8*)(Bb + j * 32);
    }
    #pragma unroll
    for (int j = 0; j < 4; ++j)
      acc = __builtin_amdgcn_mfma_f32_16x16x32_f16(mkfrag(a[j], c[j]), bfr[j], acc, 0, 0, 0);
  }
  #pragma unroll
  for (int r = 0; r < 4; ++r) red[wid][(g16 * 4 + r) * 16 + l15] = acc[r];
  __syncthreads();

  if (tid < 256) {
    float s = 0.f;
    #pragma unroll
    for (int w = 0; w < 8; ++w) s += red[w][tid];
    const int row = tid >> 4, gate = tid & 15;
    const int t = t0 + row;
    if (gate < 8) {
      ig_ws[(size_t)(b * NHD + gate) * SS + t] = s + bi[gate];
    } else {
      float ft = s + bfb[gate - 8];
      float lf = fminf(ft, 0.f) - log1pf(expf(-fabsf(ft)));
      lf_ws[(size_t)(b * NHD + gate - 8) * SS + t] = lf;
    }
  }
}

// ---------------------------------------------------------------------------
// Kernel 2: prep (validated).
// ---------------------------------------------------------------------------
__global__ __launch_bounds__(128) void prep_kernel(float* __restrict__ ws,
                                                   const float* __restrict__ m0,
                                                   float* __restrict__ out) {
  const int bh = blockIdx.x;
  const int s  = threadIdx.x;
  __shared__ float sh[128];
  __shared__ float bc2[2];
  __shared__ float mina[NC], mxga[NC], lfsa[NC];
  const float* lf = ws + OFF_LF + (size_t)bh * SS;
  const float* ig = ws + OFF_IG + (size_t)bh * SS;
  const float m0v = m0[bh];
  float m_run = m0v, LFtot = 0.f;
  for (int g = 0; g < NC; ++g) {
    const int t = g * CL + s;
    float lfv = lf[t], iv = ig[t];
    float v = lfv;
    sh[s] = v; __syncthreads();
    for (int off = 1; off < 128; off <<= 1) {
      float tv = (s >= off) ? sh[s - off] : 0.f;
      __syncthreads();
      v += tv; sh[s] = v; __syncthreads();
    }
    float Bv = v;
    float Gv = iv - Bv;
    v = Gv; sh[s] = v; __syncthreads();
    for (int off = 1; off < 128; off <<= 1) {
      float tv = (s >= off) ? sh[s - off] : -3.0e38f;
      __syncthreads();
      v = fmaxf(v, tv); sh[s] = v; __syncthreads();
    }
    float Rv = v;
    if (s == 127) { bc2[0] = Bv; bc2[1] = Rv; }
    __syncthreads();
    float Bend = bc2[0], mxG = bc2[1];
    __syncthreads();
    ws[OFF_B  + (size_t)bh * SS + t] = Bv;
    ws[OFF_G  + (size_t)bh * SS + t] = Gv;
    ws[OFF_RM + (size_t)bh * SS + t] = fmaxf(m_run, Rv);
    ws[OFF_E  + (size_t)bh * SS + t] = expf(Gv - mxG);
    if (s == 0) {
      ws[OFF_MIN + bh * NC + g] = m_run;
      mina[g] = m_run; mxga[g] = mxG; lfsa[g] = LFtot;
    }
    m_run = Bend + fmaxf(m_run, mxG);
    LFtot += Bend;
  }
  if (s == 0) {
    out[OUT_M + bh] = m_run;
    float* sc = ws + OFF_SC + bh * 80;
    float S = -3.0e38f;
    for (int g = 0; g < NC; ++g) {
      float r_g = lfsa[g] - mina[g];
      sc[g]      = expf(S + r_g);
      sc[20 + g] = expf(m0v + lfsa[g] - mina[g]);
      float s_g = mxga[g] - lfsa[g];
      float Sn = fmaxf(S, s_g);
      sc[40 + g] = expf(S - Sn);
      sc[60 + g] = expf(s_g - Sn);
      S = Sn;
    }
    float r16 = LFtot - m_run;
    sc[16] = expf(S + r16);
    sc[36] = expf(m0v + LFtot - m_run);
  }
}

// ---------------------------------------------------------------------------
// Kernel 3: MFMA U^(g) = K̂ᵀ·diag(E)·V + fused Un row-sums (validated r5).
// ---------------------------------------------------------------------------
__global__ __launch_bounds__(256, 2) void u_kernel(const float* __restrict__ k,
                                                   const float* __restrict__ v,
                                                   float* __restrict__ ws) {
  extern __shared__ char smem[];
  char* Kt = smem;
  char* Vt = smem + 32768;

  const int tid = threadIdx.x;
  const int wid = tid >> 6;
  const int lane = tid & 63;
  const int g16 = lane >> 4;
  const int l15 = lane & 15;
  const int g  = blockIdx.x & 15;
  const int bh = blockIdx.x >> 4;
  const int b = bh >> 3, hh = bh & 7;
  const size_t headoff = (size_t)b * SS * DD + (size_t)hh * SS * DHD;
  const float* kb = k + headoff + (size_t)g * CL * DHD;
  const float* vb = v + headoff + (size_t)g * CL * DHD;
  const float* E  = ws + OFF_E + (size_t)bh * SS + g * CL;

  #pragma unroll 4
  for (int it = 0; it < 16; ++it) {
    const int idx = (it << 8) + tid;
    const int c  = idx & 127;
    const int r0 = (idx >> 7) << 2;
    float e0 = E[r0] * SCALE, e1 = E[r0 + 1] * SCALE,
          e2 = E[r0 + 2] * SCALE, e3 = E[r0 + 3] * SCALE;
    float a0 = kb[(size_t)r0 * DHD + c] * e0;
    float a1 = kb[(size_t)(r0 + 1) * DHD + c] * e1;
    float a2 = kb[(size_t)(r0 + 2) * DHD + c] * e2;
    float a3 = kb[(size_t)(r0 + 3) * DHD + c] * e3;
    *(uint2*)swp(Kt, c, r0 * 2) = make_uint2(pk2h(a0, a1), pk2h(a2, a3));
    float b0 = vb[(size_t)r0 * DHD + c];
    float b1 = vb[(size_t)(r0 + 1) * DHD + c];
    float b2 = vb[(size_t)(r0 + 2) * DHD + c];
    float b3 = vb[(size_t)(r0 + 3) * DHD + c];
    *(uint2*)swp(Vt, c, r0 * 2) = make_uint2(pk2h(b0, b1), pk2h(b2, b3));
  }
  __syncthreads();

  if (tid < 128) {
    float s = 0.f;
    #pragma unroll
    for (int r8 = 0; r8 < 16; ++r8) {
      f16x8 x = *(f16x8*)swp(Kt, tid, r8 * 16);
      s += (float)x[0] + (float)x[1] + (float)x[2] + (float)x[3]
         + (float)x[4] + (float)x[5] + (float)x[6] + (float)x[7];
    }
    ws[OFF_UN + (size_t)(bh * NC + g) * DHD + tid] = s;
  }

  float* Ubuf = ws + OFF_U + (size_t)(bh * NC + g) * (DHD * DHD);
  const int it0 = wid * 2;
  #pragma unroll 1
  for (int jt = 0; jt < 8; ++jt) {
    f32x4 a0 = {0.f, 0.f, 0.f, 0.f}, a1 = {0.f, 0.f, 0.f, 0.f};
    #pragma unroll
    for (int kst = 0; kst < 4; ++kst) {
      const int byte = (kst * 32 + g16 * 8) * 2;
      f16x8 bf0 = *(f16x8*)swp(Vt, jt * 16 + l15, byte);
      f16x8 af0 = *(f16x8*)swp(Kt, it0 * 16 + l15, byte);
      f16x8 af1 = *(f16x8*)swp(Kt, (it0 + 1) * 16 + l15, byte);
      a0 = __builtin_amdgcn_mfma_f32_16x16x32_f16(af0, bf0, a0, 0, 0, 0);
      a1 = __builtin_amdgcn_mfma_f32_16x16x32_f16(af1, bf0, a1, 0, 0, 0);
    }
    #pragma unroll
    for (int reg = 0; reg < 4; ++reg) {
      Ubuf[(size_t)(it0 * 16 + g16 * 4 + reg) * DHD + jt * 16 + l15] = a0[reg];
      Ubuf[(size_t)((it0 + 1) * 16 + g16 * 4 + reg) * DHD + jt * 16 + l15] = a1[reg];
    }
  }
}

// ---------------------------------------------------------------------------
// Kernel 4: prefix combine (validated).
// ---------------------------------------------------------------------------
__global__ __launch_bounds__(256) void cprefix_kernel(const float* __restrict__ c0,
                                                      float* __restrict__ ws,
                                                      float* __restrict__ out) {
  const int bh = blockIdx.x >> 6;
  const int elem = ((blockIdx.x & 63) << 8) + threadIdx.x;
  const float* sc = ws + OFF_SC + bh * 80;
  float c0v = c0[(size_t)bh * 16384 + elem];
  float* Ub = ws + OFF_U + (size_t)bh * NC * 16384 + elem;
  float P = 0.f;
  #pragma unroll 1
  for (int g = 0; g < NC; ++g) {
    float u = Ub[(size_t)g * 16384];
    Ub[(size_t)g * 16384] = sc[g] * P + sc[20 + g] * c0v;
    P = sc[40 + g] * P + sc[60 + g] * u;
  }
  out[OUT_C + (size_t)bh * 16384 + elem] = sc[16] * P + sc[36] * c0v;
}

__global__ __launch_bounds__(128) void nprefix_kernel(const float* __restrict__ n0,
                                                      float* __restrict__ ws,
                                                      float* __restrict__ out) {
  const int bh = blockIdx.x;
  const int i = threadIdx.x;
  const float* sc = ws + OFF_SC + bh * 80;
  float n0v = n0[bh * DHD + i];
  const float* Ub = ws + OFF_UN + (size_t)bh * NC * DHD + i;
  float* Nb = ws + OFF_NIN + (size_t)bh * NC * DHD + i;
  float P = 0.f;
  #pragma unroll 1
  for (int g = 0; g < NC; ++g) {
    float u = Ub[g * DHD];
    Nb[g * DHD] = sc[g] * P + sc[20 + g] * n0v;
    P = sc[40 + g] * P + sc[60 + g] * u;
  }
  out[OUT_N + bh * DHD + i] = sc[16] * P + sc[36] * n0v;
}

// ---------------------------------------------------------------------------
// Kernel 5 (RESTRUCTURED): 512 thr / 8 waves, wave w owns s-tile w.
// P kept IN REGISTERS (packed f16 pairs); PV A-frags built via __shfl.
// LDS: one 32KB stage (Cin^T then V^T, swz) + Gs/ninS (1KB).  ~34KB -> 2x occ.
// ---------------------------------------------------------------------------
__global__ __launch_bounds__(512) void intra_kernel(
    const float* __restrict__ q, const float* __restrict__ k, const float* __restrict__ v,
    const float* __restrict__ lnw, float* __restrict__ ws, float* __restrict__ out) {
  __shared__ __attribute__((aligned(16))) char stage[32768];
  __shared__ __attribute__((aligned(16))) float Gs[128];
  __shared__ __attribute__((aligned(16))) float ninS[128];

  const int tid = threadIdx.x;
  const int wid = tid >> 6;          // 0..7 = s-tile
  const int lane = tid & 63;
  const int g16 = lane >> 4;
  const int l15 = lane & 15;
  const int g = blockIdx.x & 15;
  const int bh = blockIdx.x >> 4;
  const int b = bh >> 3, hh = bh & 7;
  const int t0 = g * CL;
  const int st = wid;
  const int stmax = st | 1;

  const size_t headoff = (size_t)b * SS * DD + (size_t)hh * SS * DHD;
  const float* qb = q + headoff;
  const float* kb = k + headoff;
  const float* vb = v + headoff;
  const float m_in = ws[OFF_MIN + bh * NC + g];

  if (tid < 128) {
    Gs[tid]   = ws[OFF_G + (size_t)bh * SS + t0 + tid];
    ninS[tid] = ws[OFF_NIN + (size_t)(bh * NC + g) * DHD + tid];
  }
  // per-lane row scalars (row s = st*16 + l15), straight from global (L2-hot)
  const int srow = st * 16 + l15;
  const float Ms_l = ws[OFF_RM + (size_t)bh * SS + t0 + srow];
  const float Bs_l = ws[OFF_B  + (size_t)bh * SS + t0 + srow];
  const float al_l = __expf(m_in - Ms_l);
  __syncthreads();

  // ---- Q fragments (B-operand for S, A-operand for QC) + qn2 ----
  f16x8 qf[4];
  float qn2 = 0.f;
  {
    const float* qrow = qb + (size_t)(t0 + srow) * DHD + g16 * 8;
    #pragma unroll
    for (int kst = 0; kst < 4; ++kst) {
      float4 a = *(const float4*)(qrow + kst * 32);
      float4 c = *(const float4*)(qrow + kst * 32 + 4);
      qf[kst] = mkfrag(a, c);
      const float* nn = &ninS[kst * 32 + g16 * 8];
      qn2 += a.x * nn[0] + a.y * nn[1] + a.z * nn[2] + a.w * nn[3]
           + c.x * nn[4] + c.y * nn[5] + c.z * nn[6] + c.w * nn[7];
    }
    qn2 += __shfl_xor(qn2, 16); qn2 += __shfl_xor(qn2, 32);
  }

  // transpose-stage a [128][128] fp32 row-major matrix into stage as f16 [col][row]
  auto stageT = [&](const float* src) {
    #pragma unroll
    for (int it = 0; it < 8; ++it) {
      const int idx = (it << 9) + tid;
      const int j = idx & 127;
      const int r0 = (idx >> 7) << 2;
      float a0 = src[(size_t)r0 * DHD + j];
      float a1 = src[(size_t)(r0 + 1) * DHD + j];
      float a2 = src[(size_t)(r0 + 2) * DHD + j];
      float a3 = src[(size_t)(r0 + 3) * DHD + j];
      *(uint2*)swp(stage, j, r0 * 2) = make_uint2(pk2h(a0, a1), pk2h(a2, a3));
    }
  };

  // ---- stage Cin^T ----
  stageT(ws + OFF_U + (size_t)(bh * NC + g) * (DHD * DHD));
  __syncthreads();

  // ---- QC: acc = Q @ Cin ----
  f32x4 acc[8];
  #pragma unroll
  for (int jt = 0; jt < 8; ++jt) {
    f32x4 a0 = {0.f, 0.f, 0.f, 0.f};
    #pragma unroll
    for (int kst = 0; kst < 4; ++kst) {
      f16x8 bfr = *(f16x8*)swp(stage, jt * 16 + l15, (kst * 32 + g16 * 8) * 2);
      a0 = __builtin_amdgcn_mfma_f32_16x16x32_f16(qf[kst], bfr, a0, 0, 0, 0);
    }
    acc[jt] = a0;
  }
  // alpha scale: row of acc reg = st*16 + g16*4 + reg -> shfl from lane g16*4+reg
  {
    float av[4];
    #pragma unroll
    for (int reg = 0; reg < 4; ++reg) av[reg] = __shfl(al_l, g16 * 4 + reg);
    #pragma unroll
    for (int jt = 0; jt < 8; ++jt) {
      acc[jt][0] *= av[0]; acc[jt][1] *= av[1];
      acc[jt][2] *= av[2]; acc[jt][3] *= av[3];
    }
  }
  __syncthreads();

  // ---- stage V^T over the same region ----
  stageT(vb + (size_t)t0 * DHD);
  __syncthreads();

  // ---- S-phase: S^T = mfma(K, Q); weight; keep P packed in registers ----
  unsigned pk[8][2];
  float qns = 0.f;
  #pragma unroll
  for (int rt = 0; rt < 8; ++rt) {
    if (rt <= stmax) {
      f16x8 kf[4];
      const float* krow = kb + (size_t)(t0 + rt * 16 + l15) * DHD + g16 * 8;
      #pragma unroll
      for (int kst = 0; kst < 4; ++kst)
        kf[kst] = mkfrag(*(const float4*)(krow + kst * 32),
                         *(const float4*)(krow + kst * 32 + 4));
      f32x4 sa = {0.f, 0.f, 0.f, 0.f};
      #pragma unroll
      for (int kst = 0; kst < 4; ++kst)
        sa = __builtin_amdgcn_mfma_f32_16x16x32_f16(kf[kst], qf[kst], sa, 0, 0, 0);
      float4 Gq = *(const float4*)&Gs[rt * 16 + g16 * 4];
      const float* Gqe = (const float*)&Gq;
      float vr[4];
      #pragma unroll
      for (int rr = 0; rr < 4; ++rr) {
        const int r = rt * 16 + g16 * 4 + rr;
        float w = (r <= srow) ? __expf(Gqe[rr] - Ms_l) * SCALE : 0.f;
        vr[rr] = sa[rr] * w;
      }
      qns += vr[0] + vr[1] + vr[2] + vr[3];
      pk[rt][0] = pk2h(vr[0], vr[1]);
      pk[rt][1] = pk2h(vr[2], vr[3]);
    }
  }
  qns += __shfl_xor(qns, 16); qns += __shfl_xor(qns, 32);
  const float pfull = qns + al_l * qn2;   // qn for row srow (uniform over g16)

  // ---- PV: acc += P @ V, A-frags rebuilt via shfl ----
  const int kmax = (stmax + 1) >> 1;
  const int srcb = ((g16 & 1) << 5) + l15;   // lane (g16s=(g16&1)*2, l15)
  const bool upper = g16 >= 2;
  #pragma unroll
  for (int kst = 0; kst < 4; ++kst) {
    if (kst < kmax) {
      unsigned l0 = __shfl(pk[2 * kst][0], srcb);
      unsigned l1 = __shfl(pk[2 * kst][1], srcb);
      unsigned l2 = __shfl(pk[2 * kst][0], srcb + 16);
      unsigned l3 = __shfl(pk[2 * kst][1], srcb + 16);
      unsigned h0 = __shfl(pk[2 * kst + 1][0], srcb);
      unsigned h1 = __shfl(pk[2 * kst + 1][1], srcb);
      unsigned h2 = __shfl(pk[2 * kst + 1][0], srcb + 16);
      unsigned h3 = __shfl(pk[2 * kst + 1][1], srcb + 16);
      union { unsigned u[4]; f16x8 h; } pa;
      pa.u[0] = upper ? h0 : l0;
      pa.u[1] = upper ? h1 : l1;
      pa.u[2] = upper ? h2 : l2;
      pa.u[3] = upper ? h3 : l3;
      #pragma unroll
      for (int jt = 0; jt < 8; ++jt) {
        f16x8 vf = *(f16x8*)swp(stage, jt * 16 + l15, (kst * 32 + g16 * 8) * 2);
        acc[jt] = __builtin_amdgcn_mfma_f32_16x16x32_f16(pa.h, vf, acc[jt], 0, 0, 0);
      }
    }
  }

  // ---- epilogue: denom, LayerNorm, store ----
  const float* lw = lnw + hh * DHD;
  float lwv[8];
  #pragma unroll
  for (int jt = 0; jt < 8; ++jt) lwv[jt] = lw[jt * 16 + l15];

  const int s0 = st * 16 + g16 * 4;
  #pragma unroll
  for (int reg = 0; reg < 4; ++reg) {
    float qn_r = __shfl(pfull, g16 * 4 + reg);
    float B_r  = __shfl(Bs_l,  g16 * 4 + reg);
    float M_r  = __shfl(Ms_l,  g16 * 4 + reg);
    float den = fmaxf(fabsf(qn_r), __expf(-(B_r + M_r))) + 1e-6f;
    float inv = 1.0f / den;
    float mp = 0.f, sp = 0.f;
    float hv[8];
    #pragma unroll
    for (int jt = 0; jt < 8; ++jt) {
      float h = acc[jt][reg] * inv;
      hv[jt] = h;
      mp += h; sp += h * h;
    }
    mp += __shfl_xor(mp, 1); sp += __shfl_xor(sp, 1);
    mp += __shfl_xor(mp, 2); sp += __shfl_xor(sp, 2);
    mp += __shfl_xor(mp, 4); sp += __shfl_xor(sp, 4);
    mp += __shfl_xor(mp, 8); sp += __shfl_xor(sp, 8);
    float mu = mp * (1.f / 128.f);
    float var = fmaxf(sp * (1.f / 128.f) - mu * mu, 0.f);
    float rstd = rsqrtf(var + 1e-6f);
    float* orow = out + (size_t)(b * SS + t0 + s0 + reg) * DD + hh * DHD;
    #pragma unroll
    for (int jt = 0; jt < 8; ++jt)
      orow[jt * 16 + l15] = (hv[jt] - mu) * rstd * lwv[jt];
  }
}

extern "C" void kernel_launch(void* const* d_in, const int* in_sizes, int n_in,
                              void* d_out, int out_size, void* d_ws, size_t ws_size,
                              hipStream_t stream) {
  const float* q   = (const float*)d_in[0];
  const float* k   = (const float*)d_in[1];
  const float* v   = (const float*)d_in[2];
  const float* c0  = (const float*)d_in[3];
  const float* n0  = (const float*)d_in[4];
  const float* m0  = (const float*)d_in[5];
  const float* Wi  = (const float*)d_in[6];
  const float* bi  = (const float*)d_in[7];
  const float* Wf  = (const float*)d_in[8];
  const float* bf  = (const float*)d_in[9];
  const float* lnw = (const float*)d_in[10];
  float* out = (float*)d_out;
  float* ws  = (float*)d_ws;

  _Float16* WT = (_Float16*)(ws + OFF_U);   // dead region until u_kernel writes it

  wtrans_kernel<<<12, 256, 0, stream>>>(Wi, Wf, WT);
  gates_kernel<<<BB * SS / 16, 512, 0, stream>>>(q, k, v, WT, bi, bf,
                                                 ws + OFF_IG, ws + OFF_LF);
  prep_kernel<<<BB * NHD, 128, 0, stream>>>(ws, m0, out);
  u_kernel<<<BB * NHD * NC, 256, 65536, stream>>>(k, v, ws);
  cprefix_kernel<<<BB * NHD * 64, 256, 0, stream>>>(c0, ws, out);
  nprefix_kernel<<<BB * NHD, 128, 0, stream>>>(n0, ws, out);
  intra_kernel<<<BB * NHD * NC, 512, 0, stream>>>(q, k, v, lnw, ws, out);
}